// Round 1
// baseline (9322.289 us; speedup 1.0000x reference)
//
#include <hip/hip_runtime.h>
#include <hip/hip_bf16.h>
#include <cstddef>

typedef __attribute__((ext_vector_type(8))) short short8;
typedef __attribute__((ext_vector_type(4))) float f32x4;
typedef unsigned short u16;
typedef unsigned int u32;

#define BM 128
#define BN 128
#define BK 32
#define LDS_PAD 40  // padded inner dim (elements); rows stay 16B-aligned

__device__ __forceinline__ u16 f2bf(float f) {
    __hip_bfloat16 b = __float2bfloat16(f);
    return *reinterpret_cast<u16*>(&b);
}

// ---------------------------------------------------------------------------
// fp32 [R][C] -> bf16 [C][R]  (weights converted + transposed once per launch)
// ---------------------------------------------------------------------------
__global__ void transpose_f32_bf16(const float* __restrict__ in,
                                   u16* __restrict__ out, int R, int C) {
    __shared__ float tile[32][33];
    int bx = blockIdx.x * 32;  // C dim
    int by = blockIdx.y * 32;  // R dim
    int tx = threadIdx.x, ty = threadIdx.y;
#pragma unroll
    for (int j = 0; j < 32; j += 8)
        tile[ty + j][tx] = in[(size_t)(by + ty + j) * C + bx + tx];
    __syncthreads();
#pragma unroll
    for (int j = 0; j < 32; j += 8)
        out[(size_t)(bx + ty + j) * R + by + tx] = f2bf(tile[tx][ty + j]);
}

// ---------------------------------------------------------------------------
// One K-loop pass of the tiled MFMA GEMM. A is [M,K] (bf16 or fp32, lda given),
// B is B^T layout: [N,K] bf16 row-major. acc += A@B over this K range.
// ---------------------------------------------------------------------------
template <bool F32A>
__device__ __forceinline__ void gemm_pass(const void* __restrict__ Av, int lda,
                                          const u16* __restrict__ B, int K,
                                          int m0, int n0, int tid,
                                          u16 (*As)[LDS_PAD], u16 (*Bs)[LDS_PAD],
                                          f32x4 (&acc)[4][4]) {
    const int lane = tid & 63;
    const int wid = tid >> 6;
    const int wrow = wid >> 1, wcol = wid & 1;
    const int r16 = lane & 15, kg = lane >> 4;

    for (int kt = 0; kt < K; kt += BK) {
        __syncthreads();
#pragma unroll
        for (int q = 0; q < 2; ++q) {
            int cidx = q * 256 + tid;
            int row = cidx >> 2;
            int koff = (cidx & 3) * 8;
            if (F32A) {
                const float* src = (const float*)Av + (size_t)(m0 + row) * lda + kt + koff;
                float4 v0 = *(const float4*)src;
                float4 v1 = *(const float4*)(src + 4);
                uint4 pk;
                pk.x = (u32)f2bf(v0.x) | ((u32)f2bf(v0.y) << 16);
                pk.y = (u32)f2bf(v0.z) | ((u32)f2bf(v0.w) << 16);
                pk.z = (u32)f2bf(v1.x) | ((u32)f2bf(v1.y) << 16);
                pk.w = (u32)f2bf(v1.z) | ((u32)f2bf(v1.w) << 16);
                *(uint4*)&As[row][koff] = pk;
            } else {
                const u16* src = (const u16*)Av + (size_t)(m0 + row) * lda + kt + koff;
                *(uint4*)&As[row][koff] = *(const uint4*)src;
            }
            const u16* bsrc = B + (size_t)(n0 + row) * K + kt + koff;
            *(uint4*)&Bs[row][koff] = *(const uint4*)bsrc;
        }
        __syncthreads();

        short8 af[4], bfr[4];
#pragma unroll
        for (int mi = 0; mi < 4; ++mi)
            af[mi] = *(const short8*)&As[wrow * 64 + mi * 16 + r16][kg * 8];
#pragma unroll
        for (int ni = 0; ni < 4; ++ni)
            bfr[ni] = *(const short8*)&Bs[wcol * 64 + ni * 16 + r16][kg * 8];
#pragma unroll
        for (int mi = 0; mi < 4; ++mi)
#pragma unroll
            for (int ni = 0; ni < 4; ++ni)
                acc[mi][ni] = __builtin_amdgcn_mfma_f32_16x16x32_bf16(
                    af[mi], bfr[ni], acc[mi][ni], 0, 0, 0);
    }
}

// C[M,N] fp32 = A1@B1 (+ A2@B2) (+ bias), optional bf16 secondary output.
template <bool A1F32, bool HAS2, bool BF16OUT>
__global__ __launch_bounds__(256) void gemm_kernel(
    const void* __restrict__ A1, int lda1, const u16* __restrict__ B1, int K1,
    const u16* __restrict__ A2, int lda2, const u16* __restrict__ B2, int K2,
    const float* __restrict__ bias, float* __restrict__ C, int ldc,
    u16* __restrict__ Cb, int ldcb) {
    __shared__ __align__(16) u16 As[BM][LDS_PAD];
    __shared__ __align__(16) u16 Bs[BN][LDS_PAD];
    const int tid = threadIdx.x;
    const int m0 = blockIdx.y * BM, n0 = blockIdx.x * BN;

    f32x4 acc[4][4] = {};
    gemm_pass<A1F32>(A1, lda1, B1, K1, m0, n0, tid, As, Bs, acc);
    if constexpr (HAS2) gemm_pass<false>(A2, lda2, B2, K2, m0, n0, tid, As, Bs, acc);

    const int lane = tid & 63;
    const int wid = tid >> 6;
    const int wrow = wid >> 1, wcol = wid & 1;
    const int r16 = lane & 15, rg = lane >> 4;
#pragma unroll
    for (int ni = 0; ni < 4; ++ni) {
        int col = n0 + wcol * 64 + ni * 16 + r16;
        float bv = bias ? bias[col] : 0.f;
#pragma unroll
        for (int mi = 0; mi < 4; ++mi) {
#pragma unroll
            for (int r = 0; r < 4; ++r) {
                int row = m0 + wrow * 64 + mi * 16 + rg * 4 + r;
                float v = acc[mi][ni][r] + bv;
                C[(size_t)row * ldc + col] = v;
                if constexpr (BF16OUT) Cb[(size_t)row * ldcb + col] = f2bf(v);
            }
        }
    }
}

// ---------------------------------------------------------------------------
// LSTM gates: z[B,8192] (i,f,g,o blocks of 2048) -> update c (fp32), h (bf16)
// ---------------------------------------------------------------------------
__global__ void lstm_pointwise(const float* __restrict__ z, float* __restrict__ c,
                               u16* __restrict__ h_bf) {
    int idx = blockIdx.x * blockDim.x + threadIdx.x;  // [0, 512*2048)
    int b = idx >> 11;
    int u = idx & 2047;
    const float* zr = z + (size_t)b * 8192;
    float zi = zr[u], zf = zr[u + 2048], zg = zr[u + 4096], zo = zr[u + 6144];
    float si = 1.f / (1.f + expf(-zi));
    float sf = 1.f / (1.f + expf(-zf));
    float so = 1.f / (1.f + expf(-zo));
    float cn = sf * c[idx] + si * tanhf(zg);
    float hn = so * tanhf(cn);
    c[idx] = cn;
    h_bf[idx] = f2bf(hn);
}

// ---------------------------------------------------------------------------
extern "C" void kernel_launch(void* const* d_in, const int* in_sizes, int n_in,
                              void* d_out, int out_size, void* d_ws, size_t ws_size,
                              hipStream_t stream) {
    const float* inputs = (const float*)d_in[0];  // [512,48,2048]
    const float* Wk = (const float*)d_in[1];      // [2048,8192]
    const float* Wr = (const float*)d_in[2];      // [2048,8192]
    const float* bias = (const float*)d_in[3];    // [8192]
    const float* Wd = (const float*)d_in[4];      // [2048,2048]
    const float* bd = (const float*)d_in[5];      // [2048]
    float* out = (float*)d_out;                   // [512,24,2048]

    char* ws = (char*)d_ws;
    u16* kT = (u16*)ws;   ws += (size_t)8192 * 2048 * 2;  // [8192][2048] bf16
    u16* rT = (u16*)ws;   ws += (size_t)8192 * 2048 * 2;  // [8192][2048] bf16
    u16* dT = (u16*)ws;   ws += (size_t)2048 * 2048 * 2;  // [2048][2048] bf16
    float* z = (float*)ws;  ws += (size_t)512 * 8192 * 4;
    float* c = (float*)ws;  ws += (size_t)512 * 2048 * 4;
    u16* h = (u16*)ws;    ws += (size_t)512 * 2048 * 2;
    u16* pred = (u16*)ws; ws += (size_t)512 * 2048 * 2;

    dim3 tb(32, 8);
    transpose_f32_bf16<<<dim3(8192 / 32, 2048 / 32), tb, 0, stream>>>(Wk, kT, 2048, 8192);
    transpose_f32_bf16<<<dim3(8192 / 32, 2048 / 32), tb, 0, stream>>>(Wr, rT, 2048, 8192);
    transpose_f32_bf16<<<dim3(2048 / 32, 2048 / 32), tb, 0, stream>>>(Wd, dT, 2048, 2048);
    hipMemsetAsync(h, 0, (size_t)512 * 2048 * 2, stream);
    hipMemsetAsync(c, 0, (size_t)512 * 2048 * 4, stream);

    dim3 gz(8192 / BN, 512 / BM);  // fused z GEMM grid (64,4)
    dim3 gp(2048 / BN, 512 / BM);  // dense pred GEMM grid (16,4)

    // warmup: 48 steps over the input window
    for (int t = 0; t < 48; ++t) {
        gemm_kernel<true, true, false><<<gz, 256, 0, stream>>>(
            inputs + (size_t)t * 2048, 48 * 2048, kT, 2048,
            h, 2048, rT, 2048, bias, z, 8192, nullptr, 0);
        lstm_pointwise<<<4096, 256, 0, stream>>>(z, c, h);
    }
    // pred0
    gemm_kernel<false, false, true><<<gp, 256, 0, stream>>>(
        h, 2048, dT, 2048, nullptr, 0, nullptr, 0, bd,
        out, 24 * 2048, pred, 2048);
    // autoregressive decode
    for (int t = 1; t < 24; ++t) {
        gemm_kernel<false, true, false><<<gz, 256, 0, stream>>>(
            pred, 2048, kT, 2048, h, 2048, rT, 2048, bias, z, 8192, nullptr, 0);
        lstm_pointwise<<<4096, 256, 0, stream>>>(z, c, h);
        gemm_kernel<false, false, true><<<gp, 256, 0, stream>>>(
            h, 2048, dT, 2048, nullptr, 0, nullptr, 0, bd,
            out + (size_t)t * 2048, 24 * 2048, pred, 2048);
    }
}

// Round 2
// 6059.636 us; speedup vs baseline: 1.5384x; 1.5384x over previous
//
#include <hip/hip_runtime.h>
#include <hip/hip_bf16.h>
#include <cstddef>
#include <cstdint>

typedef __attribute__((ext_vector_type(8))) short short8;
typedef __attribute__((ext_vector_type(4))) float f32x4;
typedef unsigned short u16;
typedef unsigned int u32;

#define B_ 512
#define T_ 48
#define F_ 2048
#define U_ 2048
#define G4 8192
#define OT 24

__device__ __forceinline__ u16 f2bf(float f) {
    __hip_bfloat16 b = __float2bfloat16(f);
    return *reinterpret_cast<u16*>(&b);
}
__device__ __forceinline__ float bf2f(u16 v) {
    union { u32 u; float f; } c;
    c.u = ((u32)v) << 16;
    return c.f;
}

__device__ __forceinline__ void gl_lds16(const void* g, void* l) {
    __builtin_amdgcn_global_load_lds(
        (const __attribute__((address_space(1))) void*)g,
        (__attribute__((address_space(3))) void*)l, 16, 0, 0);
}

// ---------------------------------------------------------------------------
// fp32 [R][C] -> bf16 [C][R]
// ---------------------------------------------------------------------------
__global__ void transpose_f32_bf16(const float* __restrict__ in,
                                   u16* __restrict__ out, int R, int C) {
    __shared__ float tile[32][33];
    int bx = blockIdx.x * 32;  // C dim
    int by = blockIdx.y * 32;  // R dim
    int tx = threadIdx.x, ty = threadIdx.y;
#pragma unroll
    for (int j = 0; j < 32; j += 8)
        tile[ty + j][tx] = in[(size_t)(by + ty + j) * C + bx + tx];
    __syncthreads();
#pragma unroll
    for (int j = 0; j < 32; j += 8)
        out[(size_t)(bx + ty + j) * R + by + tx] = f2bf(tile[tx][ty + j]);
}

// flat fp32 -> bf16 (n multiple of 4)
__global__ void cvt_bf16(const float* __restrict__ in, u16* __restrict__ out, long n) {
    long i = ((long)blockIdx.x * blockDim.x + threadIdx.x) * 4;
    if (i >= n) return;
    f32x4 v = *(const f32x4*)(in + i);
    ushort4 o;
    o.x = f2bf(v[0]); o.y = f2bf(v[1]); o.z = f2bf(v[2]); o.w = f2bf(v[3]);
    *(ushort4*)(out + i) = o;
}

// bcomb[n] = bias[n] + dot(bd, Wk[:,n])  via kT rows (bf16)
__global__ void bcomb_k(const u16* __restrict__ kT, const float* __restrict__ bd,
                        const float* __restrict__ bias, float* __restrict__ bc) {
    int lane = threadIdx.x & 63, wid = threadIdx.x >> 6;
    int n = blockIdx.x * 4 + wid;
    const u16* row = kT + (size_t)n * U_;
    float s = 0.f;
    for (int j0 = lane * 8; j0 < U_; j0 += 512) {
        short8 v = *(const short8*)&row[j0];
#pragma unroll
        for (int e = 0; e < 8; ++e) s += bd[j0 + e] * bf2f((u16)v[e]);
    }
#pragma unroll
    for (int o = 32; o; o >>= 1) s += __shfl_down(s, o);
    if (lane == 0) bc[n] = bias[n] + s;
}

// ---------------------------------------------------------------------------
// m97-style GEMM pass: A [M,K] bf16 row-major (lda), B^T [N,K] bf16 (ldb=K).
// Linear LDS, global_load_lds width-16, BK=32, 4 waves in 2x2 grid.
// ---------------------------------------------------------------------------
template <int BM, int BN>
__device__ __forceinline__ void gpass(const u16* __restrict__ A, long lda,
                                      const u16* __restrict__ B, int K,
                                      int m0, int n0, int tid,
                                      u16* As, u16* Bs,
                                      f32x4 (&acc)[BM / 32][BN / 32]) {
    const int lane = tid & 63, wid = tid >> 6;
    const int wr = wid >> 1, wc = wid & 1;
    const int r16 = lane & 15, kg = lane >> 4;
    constexpr int MF = BM / 32, NF = BN / 32;
    constexpr int AIS = (BM * 64) / 4096, BIS = (BN * 64) / 4096;
    const int lrow = lane >> 2;
    const int ke = (lane & 3) * 8;
    const u16* Ab = A + (size_t)m0 * lda + ke;
    const u16* Bb = B + (size_t)n0 * (size_t)K + ke;

    for (int kt = 0; kt < K; kt += 32) {
        __syncthreads();
#pragma unroll
        for (int i = 0; i < AIS; ++i) {
            int row = i * 64 + wid * 16 + lrow;
            gl_lds16(Ab + (size_t)row * lda + kt, As + (i * 4096 + wid * 1024) / 2);
        }
#pragma unroll
        for (int i = 0; i < BIS; ++i) {
            int row = i * 64 + wid * 16 + lrow;
            gl_lds16(Bb + (size_t)row * (size_t)K + kt, Bs + (i * 4096 + wid * 1024) / 2);
        }
        __syncthreads();

        short8 af[MF], bfv[NF];
#pragma unroll
        for (int mi = 0; mi < MF; ++mi)
            af[mi] = *(const short8*)&As[(wr * (BM / 2) + mi * 16 + r16) * 32 + kg * 8];
#pragma unroll
        for (int ni = 0; ni < NF; ++ni)
            bfv[ni] = *(const short8*)&Bs[(wc * (BN / 2) + ni * 16 + r16) * 32 + kg * 8];
#pragma unroll
        for (int mi = 0; mi < MF; ++mi)
#pragma unroll
            for (int ni = 0; ni < NF; ++ni)
                acc[mi][ni] = __builtin_amdgcn_mfma_f32_16x16x32_bf16(
                    af[mi], bfv[ni], acc[mi][ni], 0, 0, 0);
    }
}

// CM: 0 none, 1 fp32 Cinit, 2 bf16 Cinit. OUTM: 0 fp32, 1 bf16,
// 2 fp32 with (t,b) output remap, 3 fp32 (ldc) + bf16 secondary (ldc2).
template <int BM, int BN, int CM, int HAS2, int BIAS, int OUTM>
__global__ __launch_bounds__(256) void gemm2(
    const u16* __restrict__ A1, long lda1, const u16* __restrict__ B1, int K1,
    const u16* __restrict__ A2, long lda2, const u16* __restrict__ B2, int K2,
    const void* __restrict__ Ci, long ldci, const float* __restrict__ bias,
    void* __restrict__ Co, long ldc, void* __restrict__ Co2, long ldc2) {
    __shared__ __align__(16) u16 As[BM * 32];
    __shared__ __align__(16) u16 Bs[BN * 32];
    const int gx = gridDim.x;
    const int nwg = gx * gridDim.y;
    int lin = blockIdx.y * gx + blockIdx.x;
    if ((nwg & 7) == 0) {  // bijective XCD swizzle
        int q = nwg >> 3;
        lin = (lin & 7) * q + (lin >> 3);
    }
    const int m0 = (lin / gx) * BM, n0 = (lin % gx) * BN;
    const int tid = threadIdx.x;

    f32x4 acc[BM / 32][BN / 32] = {};
    gpass<BM, BN>(A1, lda1, B1, K1, m0, n0, tid, As, Bs, acc);
    if constexpr (HAS2) gpass<BM, BN>(A2, lda2, B2, K2, m0, n0, tid, As, Bs, acc);

    const int lane = tid & 63, wid = tid >> 6;
    const int wr = wid >> 1, wc = wid & 1, r16 = lane & 15, rg = lane >> 4;
#pragma unroll
    for (int ni = 0; ni < BN / 32; ++ni) {
        int col = n0 + wc * (BN / 2) + ni * 16 + r16;
        float bv = BIAS ? bias[col] : 0.f;
#pragma unroll
        for (int mi = 0; mi < BM / 32; ++mi) {
#pragma unroll
            for (int r = 0; r < 4; ++r) {
                int row = m0 + wr * (BM / 2) + mi * 16 + rg * 4 + r;
                float v = acc[mi][ni][r] + bv;
                if constexpr (CM == 1) v += ((const float*)Ci)[(size_t)row * ldci + col];
                if constexpr (CM == 2) v += bf2f(((const u16*)Ci)[(size_t)row * ldci + col]);
                if constexpr (OUTM == 0) ((float*)Co)[(size_t)row * ldc + col] = v;
                if constexpr (OUTM == 1) ((u16*)Co)[(size_t)row * ldc + col] = f2bf(v);
                if constexpr (OUTM == 2) {
                    int t = row >> 9, b = row & 511;
                    ((float*)Co)[((size_t)b * OT + t) * F_ + col] = v;
                }
                if constexpr (OUTM == 3) {
                    ((float*)Co)[(size_t)row * ldc + col] = v;
                    ((u16*)Co2)[(size_t)row * ldc2 + col] = f2bf(v);
                }
            }
        }
    }
}

// ---------------------------------------------------------------------------
// LSTM gates, vectorized x4: z[B,8192] -> c (fp32), h (bf16)
// ---------------------------------------------------------------------------
__global__ void lstm_pw(const float* __restrict__ z, float* __restrict__ c,
                        u16* __restrict__ h) {
    int i4 = (blockIdx.x * blockDim.x + threadIdx.x) * 4;
    int b = i4 >> 11, u = i4 & 2047;
    const float* zr = z + (size_t)b * G4 + u;
    f32x4 zi = *(const f32x4*)(zr);
    f32x4 zf = *(const f32x4*)(zr + U_);
    f32x4 zg = *(const f32x4*)(zr + 2 * U_);
    f32x4 zo = *(const f32x4*)(zr + 3 * U_);
    f32x4 cv = *(f32x4*)(c + i4);
    f32x4 cn;
    ushort4 hb;
    u16* hp = &hb.x;
#pragma unroll
    for (int e = 0; e < 4; ++e) {
        float si = 1.f / (1.f + __expf(-zi[e]));
        float sf = 1.f / (1.f + __expf(-zf[e]));
        float so = 1.f / (1.f + __expf(-zo[e]));
        float cc = sf * cv[e] + si * tanhf(zg[e]);
        cn[e] = cc;
        hp[e] = f2bf(so * tanhf(cc));
    }
    *(f32x4*)(c + i4) = cn;
    *(ushort4*)(h + i4) = hb;
}

// ---------------------------------------------------------------------------
extern "C" void kernel_launch(void* const* d_in, const int* in_sizes, int n_in,
                              void* d_out, int out_size, void* d_ws, size_t ws_size,
                              hipStream_t stream) {
    const float* x = (const float*)d_in[0];     // [512,48,2048]
    const float* Wk = (const float*)d_in[1];    // [2048,8192]
    const float* Wr = (const float*)d_in[2];    // [2048,8192]
    const float* bias = (const float*)d_in[3];  // [8192]
    const float* Wd = (const float*)d_in[4];    // [2048,2048]
    const float* bd = (const float*)d_in[5];    // [2048]
    float* out = (float*)d_out;                 // [512,24,2048]

    // d_out doubles as bf16-x storage: dead before any output write.
    u16* xbf = (u16*)d_out;  // 24576x2048 bf16 == 100,663,296 B == sizeof(out)

    auto pad = [](size_t s) { return (s + 255) & ~(size_t)255; };
    const size_t szKT = (size_t)G4 * U_ * 2, szRT = szKT, szWC = szKT;
    const size_t szDT = (size_t)U_ * F_ * 2, szDBF = szDT;
    const size_t szBC = (size_t)G4 * 4;
    const size_t szH = (size_t)OT * B_ * U_ * 2;
    const size_t szC = (size_t)B_ * U_ * 4;
    const size_t szZ = (size_t)B_ * G4 * 4;
    const size_t szPred = (size_t)B_ * U_ * 2;
    const size_t szZX = (size_t)B_ * T_ * G4 * 4;
    const size_t SLOT = (size_t)B_ * U_;  // H slot stride, elements

    const size_t needP1 = pad(szKT) + pad(szRT) + pad(szDT) + pad(szDBF) +
                          pad(szWC) + pad(szBC) + pad(szH) + pad(szC) + pad(szZ);
    const size_t needP3 = needP1 + pad(szZX);
    const int path = ws_size >= needP3 ? 3 : (ws_size >= needP1 ? 1 : 0);

    char* p = (char*)d_ws;
    auto alloc = [&](size_t bytes) { void* r = p; p += (bytes + 255) & ~(size_t)255; return r; };

    dim3 tb32(32, 8);
    const dim3 gz(G4 / 128, B_ / 64);    // serial z-GEMM grid (64,8)
    const long ldaX = (long)T_ * F_;

    if (path >= 1) {
        u16* kT = (u16*)alloc(szKT);
        u16* rT = (u16*)alloc(szRT);
        u16* dT = (u16*)alloc(szDT);
        u16* dbf = (u16*)alloc(szDBF);
        u16* WcT = (u16*)alloc(szWC);
        float* bc = (float*)alloc(szBC);
        u16* H = (u16*)alloc(szH);
        float* c = (float*)alloc(szC);
        float* z = (float*)alloc(szZ);
        float* ZX = path == 3 ? (float*)alloc(szZX) : nullptr;

        cvt_bf16<<<(B_ * T_ * F_ / 4 + 255) / 256, 256, 0, stream>>>(x, xbf, (long)B_ * T_ * F_);
        transpose_f32_bf16<<<dim3(G4 / 32, F_ / 32), tb32, 0, stream>>>(Wk, kT, F_, G4);
        transpose_f32_bf16<<<dim3(G4 / 32, U_ / 32), tb32, 0, stream>>>(Wr, rT, U_, G4);
        transpose_f32_bf16<<<dim3(F_ / 32, U_ / 32), tb32, 0, stream>>>(Wd, dT, U_, F_);
        cvt_bf16<<<(U_ * F_ / 4 + 255) / 256, 256, 0, stream>>>(Wd, dbf, (long)U_ * F_);
        bcomb_k<<<G4 / 4, 256, 0, stream>>>(kT, bd, bias, bc);

        // WcombT[n][k] = Wr[k][n] + sum_j Wk[j][n]*Wd[k][j]  (A=kT, B^T=dbf, Ci=rT)
        gemm2<128, 128, 2, 0, 0, 1><<<dim3(U_ / 128, G4 / 128), 256, 0, stream>>>(
            kT, U_, dbf, F_, nullptr, 0, nullptr, 0, rT, U_, nullptr, WcT, U_, nullptr, 0);

        if (path == 3) {
            // ZX = xbf @ Wk + bias  (all 48 steps at once)
            gemm2<128, 128, 0, 0, 1, 0><<<dim3(G4 / 128, B_ * T_ / 128), 256, 0, stream>>>(
                xbf, F_, kT, F_, nullptr, 0, nullptr, 0, nullptr, 0, bias, ZX, G4, nullptr, 0);
        }
        hipMemsetAsync(c, 0, szC, stream);
        hipMemsetAsync(H, 0, (size_t)B_ * U_ * 2, stream);  // h0 = 0

        for (int t = 0; t < T_; ++t) {
            if (path == 3) {
                gemm2<64, 128, 1, 0, 0, 0><<<gz, 256, 0, stream>>>(
                    H, U_, rT, U_, nullptr, 0, nullptr, 0,
                    ZX + (size_t)t * G4, (long)T_ * G4, nullptr, z, G4, nullptr, 0);
            } else {
                gemm2<64, 128, 0, 1, 1, 0><<<gz, 256, 0, stream>>>(
                    xbf + (size_t)t * F_, ldaX, kT, F_, H, U_, rT, U_,
                    nullptr, 0, bias, z, G4, nullptr, 0);
            }
            lstm_pw<<<B_ * U_ / 4 / 256, 256, 0, stream>>>(z, c, H);
        }
        for (int t = 1; t < OT; ++t) {
            gemm2<64, 128, 0, 0, 1, 0><<<gz, 256, 0, stream>>>(
                H + (size_t)(t - 1) * SLOT, U_, WcT, U_, nullptr, 0, nullptr, 0,
                nullptr, 0, bc, z, G4, nullptr, 0);
            lstm_pw<<<B_ * U_ / 4 / 256, 256, 0, stream>>>(z, c, H + (size_t)t * SLOT);
        }
        // all preds in one GEMM: out[b][t][f] = H[t*512+b] @ Wd + bd
        gemm2<128, 128, 0, 0, 1, 2><<<dim3(F_ / 128, OT * B_ / 128), 256, 0, stream>>>(
            H, U_, dT, U_, nullptr, 0, nullptr, 0, nullptr, 0, bd, out, F_, nullptr, 0);
    } else {
        // Fallback: round-0 footprint (~101 MB) with the upgraded GEMM.
        u16* kT = (u16*)alloc(szKT);
        u16* rT = (u16*)alloc(szRT);
        u16* dT = (u16*)alloc(szDT);
        float* z = (float*)alloc(szZ);
        float* c = (float*)alloc(szC);
        u16* h = (u16*)alloc(szPred);
        u16* pred = (u16*)alloc(szPred);

        cvt_bf16<<<(B_ * T_ * F_ / 4 + 255) / 256, 256, 0, stream>>>(x, xbf, (long)B_ * T_ * F_);
        transpose_f32_bf16<<<dim3(G4 / 32, F_ / 32), tb32, 0, stream>>>(Wk, kT, F_, G4);
        transpose_f32_bf16<<<dim3(G4 / 32, U_ / 32), tb32, 0, stream>>>(Wr, rT, U_, G4);
        transpose_f32_bf16<<<dim3(F_ / 32, U_ / 32), tb32, 0, stream>>>(Wd, dT, U_, F_);
        hipMemsetAsync(c, 0, szC, stream);
        hipMemsetAsync(h, 0, szPred, stream);

        for (int t = 0; t < T_; ++t) {
            gemm2<64, 128, 0, 1, 1, 0><<<gz, 256, 0, stream>>>(
                xbf + (size_t)t * F_, ldaX, kT, F_, h, U_, rT, U_,
                nullptr, 0, bias, z, G4, nullptr, 0);
            lstm_pw<<<B_ * U_ / 4 / 256, 256, 0, stream>>>(z, c, h);
        }
        // pred0 -> out[:,0,:] and bf16 pred
        gemm2<64, 128, 0, 0, 1, 3><<<dim3(F_ / 128, B_ / 64), 256, 0, stream>>>(
            h, U_, dT, U_, nullptr, 0, nullptr, 0, nullptr, 0, bd,
            out, (long)OT * F_, pred, U_);
        for (int t = 1; t < OT; ++t) {
            gemm2<64, 128, 0, 1, 1, 0><<<gz, 256, 0, stream>>>(
                pred, U_, kT, F_, h, U_, rT, U_, nullptr, 0, bias, z, G4, nullptr, 0);
            lstm_pw<<<B_ * U_ / 4 / 256, 256, 0, stream>>>(z, c, h);
            gemm2<64, 128, 0, 0, 1, 3><<<dim3(F_ / 128, B_ / 64), 256, 0, stream>>>(
                h, U_, dT, U_, nullptr, 0, nullptr, 0, nullptr, 0, bd,
                out + (size_t)t * F_, (long)OT * F_, pred, U_);
        }
    }
}

// Round 3
// 5324.695 us; speedup vs baseline: 1.7508x; 1.1380x over previous
//
#include <hip/hip_runtime.h>
#include <hip/hip_bf16.h>
#include <cstddef>
#include <cstdint>

typedef __attribute__((ext_vector_type(8))) short short8;
typedef __attribute__((ext_vector_type(4))) float f32x4;
typedef unsigned short u16;
typedef unsigned int u32;

#define B_ 512
#define T_ 48
#define F_ 2048
#define U_ 2048
#define G4 8192
#define OT 24

__device__ __forceinline__ u16 f2bf(float f) {
    __hip_bfloat16 b = __float2bfloat16(f);
    return *reinterpret_cast<u16*>(&b);
}
__device__ __forceinline__ float bf2f(u16 v) {
    union { u32 u; float f; } c;
    c.u = ((u32)v) << 16;
    return c.f;
}

__device__ __forceinline__ void gl_lds16(const void* g, void* l) {
    __builtin_amdgcn_global_load_lds(
        (const __attribute__((address_space(1))) void*)g,
        (__attribute__((address_space(3))) void*)l, 16, 0, 0);
}

// ---------------------------------------------------------------------------
// fp32 [R][C] -> bf16 [C][R]
// ---------------------------------------------------------------------------
__global__ void transpose_f32_bf16(const float* __restrict__ in,
                                   u16* __restrict__ out, int R, int C) {
    __shared__ float tile[32][33];
    int bx = blockIdx.x * 32;
    int by = blockIdx.y * 32;
    int tx = threadIdx.x, ty = threadIdx.y;
#pragma unroll
    for (int j = 0; j < 32; j += 8)
        tile[ty + j][tx] = in[(size_t)(by + ty + j) * C + bx + tx];
    __syncthreads();
#pragma unroll
    for (int j = 0; j < 32; j += 8)
        out[(size_t)(bx + ty + j) * R + by + tx] = f2bf(tile[tx][ty + j]);
}

// flat fp32 -> bf16
__global__ void cvt_bf16(const float* __restrict__ in, u16* __restrict__ out, long n) {
    long i = ((long)blockIdx.x * blockDim.x + threadIdx.x) * 4;
    if (i >= n) return;
    f32x4 v = *(const f32x4*)(in + i);
    ushort4 o;
    o.x = f2bf(v[0]); o.y = f2bf(v[1]); o.z = f2bf(v[2]); o.w = f2bf(v[3]);
    *(ushort4*)(out + i) = o;
}

// x [b][t][f] fp32 -> xbf [t][b][f] bf16
__global__ void cvt_x_tmajor(const float* __restrict__ x, u16* __restrict__ xbf) {
    long i = ((long)blockIdx.x * blockDim.x + threadIdx.x) * 4;
    int f = (int)(i & (F_ - 1));
    long bt = i >> 11;
    int t = (int)(bt % T_);
    int b = (int)(bt / T_);
    f32x4 v = *(const f32x4*)(x + i);
    ushort4 o;
    o.x = f2bf(v[0]); o.y = f2bf(v[1]); o.z = f2bf(v[2]); o.w = f2bf(v[3]);
    *(ushort4*)(xbf + ((size_t)t * B_ + b) * F_ + f) = o;
}

// bcomb[n] = bias[n] + dot(bd, Wk[:,n])  via kT rows (bf16)
__global__ void bcomb_k(const u16* __restrict__ kT, const float* __restrict__ bd,
                        const float* __restrict__ bias, float* __restrict__ bc) {
    int lane = threadIdx.x & 63, wid = threadIdx.x >> 6;
    int n = blockIdx.x * 4 + wid;
    const u16* row = kT + (size_t)n * U_;
    float s = 0.f;
    for (int j0 = lane * 8; j0 < U_; j0 += 512) {
        short8 v = *(const short8*)&row[j0];
#pragma unroll
        for (int e = 0; e < 8; ++e) s += bd[j0 + e] * bf2f((u16)v[e]);
    }
#pragma unroll
    for (int o = 32; o; o >>= 1) s += __shfl_down(s, o);
    if (lane == 0) bc[n] = bias[n] + s;
}

// ---------------------------------------------------------------------------
// 2-phase double-buffered GEMM pass (T3-minimum recipe).
// A [M,K] bf16 (lda), B^T [N,K] bf16 (ldb=K). acc += A@B.
// ---------------------------------------------------------------------------
template <int BM, int BN>
__device__ __forceinline__ void gpass(const u16* __restrict__ A, long lda,
                                      const u16* __restrict__ B, int K,
                                      int m0, int n0, int tid,
                                      u16* As, u16* Bs,
                                      f32x4 (&acc)[BM / 32][BN / 32]) {
    const int lane = tid & 63, wid = tid >> 6;
    const int wr = wid >> 1, wc = wid & 1;
    const int r16 = lane & 15, kg = lane >> 4;
    constexpr int MF = BM / 32, NF = BN / 32;
    constexpr int AIS = (BM * 64) / 4096, BIS = (BN * 64) / 4096;
    constexpr int ABUF = BM * 32, BBUF = BN * 32;  // elements per buffer
    const int lrow = lane >> 2;
    const int ke = (lane & 3) * 8;
    const u16* Ab = A + (size_t)m0 * lda + ke;
    const u16* Bb = B + (size_t)n0 * (size_t)K + ke;

    auto stage = [&](int kt, int buf) {
#pragma unroll
        for (int i = 0; i < AIS; ++i) {
            int row = i * 64 + wid * 16 + lrow;
            gl_lds16(Ab + (size_t)row * lda + kt,
                     As + buf * ABUF + (i * 4096 + wid * 1024) / 2);
        }
#pragma unroll
        for (int i = 0; i < BIS; ++i) {
            int row = i * 64 + wid * 16 + lrow;
            gl_lds16(Bb + (size_t)row * (size_t)K + kt,
                     Bs + buf * BBUF + (i * 4096 + wid * 1024) / 2);
        }
    };
    auto compute = [&](int buf) {
        short8 af[MF], bfv[NF];
#pragma unroll
        for (int mi = 0; mi < MF; ++mi)
            af[mi] = *(const short8*)&As[buf * ABUF + (wr * (BM / 2) + mi * 16 + r16) * 32 + kg * 8];
#pragma unroll
        for (int ni = 0; ni < NF; ++ni)
            bfv[ni] = *(const short8*)&Bs[buf * BBUF + (wc * (BN / 2) + ni * 16 + r16) * 32 + kg * 8];
        __builtin_amdgcn_s_setprio(1);
#pragma unroll
        for (int mi = 0; mi < MF; ++mi)
#pragma unroll
            for (int ni = 0; ni < NF; ++ni)
                acc[mi][ni] = __builtin_amdgcn_mfma_f32_16x16x32_bf16(
                    af[mi], bfv[ni], acc[mi][ni], 0, 0, 0);
        __builtin_amdgcn_s_setprio(0);
    };

    __syncthreads();  // protect LDS from a previous pass
    stage(0, 0);
    __syncthreads();  // implicit vmcnt(0) drain
    int cur = 0;
    for (int kt = 32; kt < K; kt += 32) {
        stage(kt, cur ^ 1);   // prefetch next tile (latency hidden by compute)
        compute(cur);
        __syncthreads();      // drain prefetch, release read buffer
        cur ^= 1;
    }
    compute(cur);
}

// CM: 0 none, 1 fp32 Cinit, 2 bf16 Cinit. OUTM: 0 fp32, 1 bf16,
// 2 fp32 with (t,b) output remap, 3 fp32 (ldc) + bf16 secondary (ldc2).
template <int BM, int BN, int CM, int HAS2, int BIAS, int OUTM>
__global__ __launch_bounds__(256) void gemm2(
    const u16* __restrict__ A1, long lda1, const u16* __restrict__ B1, int K1,
    const u16* __restrict__ A2, long lda2, const u16* __restrict__ B2, int K2,
    const void* __restrict__ Ci, long ldci, const float* __restrict__ bias,
    void* __restrict__ Co, long ldc, void* __restrict__ Co2, long ldc2) {
    __shared__ __align__(16) u16 As[2 * BM * 32];
    __shared__ __align__(16) u16 Bs[2 * BN * 32];
    const int gx = gridDim.x;
    const int nwg = gx * gridDim.y;
    int lin = blockIdx.y * gx + blockIdx.x;
    if ((nwg & 7) == 0) {  // bijective XCD swizzle
        int q = nwg >> 3;
        lin = (lin & 7) * q + (lin >> 3);
    }
    const int m0 = (lin / gx) * BM, n0 = (lin % gx) * BN;
    const int tid = threadIdx.x;

    f32x4 acc[BM / 32][BN / 32] = {};
    gpass<BM, BN>(A1, lda1, B1, K1, m0, n0, tid, As, Bs, acc);
    if constexpr (HAS2) gpass<BM, BN>(A2, lda2, B2, K2, m0, n0, tid, As, Bs, acc);

    const int lane = tid & 63, wid = tid >> 6;
    const int wr = wid >> 1, wc = wid & 1, r16 = lane & 15, rg = lane >> 4;
#pragma unroll
    for (int ni = 0; ni < BN / 32; ++ni) {
        int col = n0 + wc * (BN / 2) + ni * 16 + r16;
        float bv = BIAS ? bias[col] : 0.f;
#pragma unroll
        for (int mi = 0; mi < BM / 32; ++mi) {
#pragma unroll
            for (int r = 0; r < 4; ++r) {
                int row = m0 + wr * (BM / 2) + mi * 16 + rg * 4 + r;
                float v = acc[mi][ni][r] + bv;
                if constexpr (CM == 1) v += ((const float*)Ci)[(size_t)row * ldci + col];
                if constexpr (CM == 2) v += bf2f(((const u16*)Ci)[(size_t)row * ldci + col]);
                if constexpr (OUTM == 0) ((float*)Co)[(size_t)row * ldc + col] = v;
                if constexpr (OUTM == 1) ((u16*)Co)[(size_t)row * ldc + col] = f2bf(v);
                if constexpr (OUTM == 2) {
                    int t = row >> 9, b = row & 511;
                    ((float*)Co)[((size_t)b * OT + t) * F_ + col] = v;
                }
                if constexpr (OUTM == 3) {
                    ((float*)Co)[(size_t)row * ldc + col] = v;
                    ((u16*)Co2)[(size_t)row * ldc2 + col] = f2bf(v);
                }
            }
        }
    }
}

// ---------------------------------------------------------------------------
// LSTM gates, vectorized x4: z[B,8192] -> c (fp32), h (bf16)
// ---------------------------------------------------------------------------
__global__ void lstm_pw(const float* __restrict__ z, float* __restrict__ c,
                        u16* __restrict__ h) {
    int i4 = (blockIdx.x * blockDim.x + threadIdx.x) * 4;
    int b = i4 >> 11, u = i4 & 2047;
    const float* zr = z + (size_t)b * G4 + u;
    f32x4 zi = *(const f32x4*)(zr);
    f32x4 zf = *(const f32x4*)(zr + U_);
    f32x4 zg = *(const f32x4*)(zr + 2 * U_);
    f32x4 zo = *(const f32x4*)(zr + 3 * U_);
    f32x4 cv = *(f32x4*)(c + i4);
    f32x4 cn;
    ushort4 hb;
    u16* hp = &hb.x;
#pragma unroll
    for (int e = 0; e < 4; ++e) {
        float si = 1.f / (1.f + __expf(-zi[e]));
        float sf = 1.f / (1.f + __expf(-zf[e]));
        float so = 1.f / (1.f + __expf(-zo[e]));
        float cc = sf * cv[e] + si * tanhf(zg[e]);
        cn[e] = cc;
        hp[e] = f2bf(so * tanhf(cc));
    }
    *(f32x4*)(c + i4) = cn;
    *(ushort4*)(h + i4) = hb;
}

// ---------------------------------------------------------------------------
extern "C" void kernel_launch(void* const* d_in, const int* in_sizes, int n_in,
                              void* d_out, int out_size, void* d_ws, size_t ws_size,
                              hipStream_t stream) {
    const float* x = (const float*)d_in[0];
    const float* Wk = (const float*)d_in[1];
    const float* Wr = (const float*)d_in[2];
    const float* bias = (const float*)d_in[3];
    const float* Wd = (const float*)d_in[4];
    const float* bd = (const float*)d_in[5];
    float* out = (float*)d_out;

    // d_out doubles as bf16-x storage (t-major): dead before any output write.
    u16* xbf = (u16*)d_out;

    auto pad = [](size_t s) { return (s + 255) & ~(size_t)255; };
    const size_t szKT = (size_t)G4 * U_ * 2, szRT = szKT, szWC = szKT;
    const size_t szDT = (size_t)U_ * F_ * 2, szDBF = szDT;
    const size_t szBC = (size_t)G4 * 4;
    const size_t szH = (size_t)OT * B_ * U_ * 2;
    const size_t szC = (size_t)B_ * U_ * 4;
    const size_t szZ = (size_t)B_ * G4 * 4;
    const size_t szPred = (size_t)B_ * U_ * 2;
    const size_t szZXstep = (size_t)B_ * G4 * 4;  // 16.78 MB / step
    const size_t SLOT = (size_t)B_ * U_;

    const size_t needP1 = pad(szKT) + pad(szRT) + pad(szDT) + pad(szDBF) +
                          pad(szWC) + pad(szBC) + pad(szH) + pad(szC) + pad(szZ);
    const int path = ws_size >= needP1 ? 1 : 0;

    char* p = (char*)d_ws;
    auto alloc = [&](size_t bytes) { void* r = p; p += (bytes + 255) & ~(size_t)255; return r; };

    dim3 tb32(32, 8);
    const dim3 gz(G4 / 128, B_ / 64);  // serial z-GEMM grid (64,8)

    if (path == 1) {
        u16* kT = (u16*)alloc(szKT);
        u16* rT = (u16*)alloc(szRT);
        u16* dT = (u16*)alloc(szDT);
        u16* dbf = (u16*)alloc(szDBF);
        u16* WcT = (u16*)alloc(szWC);
        float* bc = (float*)alloc(szBC);
        u16* H = (u16*)alloc(szH);
        float* c = (float*)alloc(szC);
        float* z = (float*)alloc(szZ);

        size_t avail = ws_size - (size_t)(p - (char*)d_ws);
        int chunk = (int)(avail / szZXstep);
        if (chunk > T_) chunk = T_;
        float* ZX = chunk >= 1 ? (float*)alloc((size_t)chunk * szZXstep) : nullptr;

        cvt_x_tmajor<<<(B_ * T_ * F_ / 4 + 255) / 256, 256, 0, stream>>>(x, xbf);
        transpose_f32_bf16<<<dim3(G4 / 32, F_ / 32), tb32, 0, stream>>>(Wk, kT, F_, G4);
        transpose_f32_bf16<<<dim3(G4 / 32, U_ / 32), tb32, 0, stream>>>(Wr, rT, U_, G4);
        transpose_f32_bf16<<<dim3(F_ / 32, U_ / 32), tb32, 0, stream>>>(Wd, dT, U_, F_);
        cvt_bf16<<<(U_ * F_ / 4 + 255) / 256, 256, 0, stream>>>(Wd, dbf, (long)U_ * F_);
        bcomb_k<<<G4 / 4, 256, 0, stream>>>(kT, bd, bias, bc);

        // WcombT[n][k] = Wr[k][n] + sum_j Wk[j][n]*Wd[k][j]
        gemm2<128, 128, 2, 0, 0, 1><<<dim3(U_ / 128, G4 / 128), 256, 0, stream>>>(
            kT, U_, dbf, F_, nullptr, 0, nullptr, 0, rT, U_, nullptr, WcT, U_, nullptr, 0);

        hipMemsetAsync(c, 0, szC, stream);
        hipMemsetAsync(H, 0, (size_t)B_ * U_ * 2, stream);

        if (chunk >= 1) {
            for (int t0 = 0; t0 < T_; t0 += chunk) {
                int nc = chunk < T_ - t0 ? chunk : T_ - t0;
                // ZX[tt][b] = x_t @ Wk + bias  for tt in [t0, t0+nc)
                gemm2<128, 128, 0, 0, 1, 0><<<dim3(G4 / 128, nc * B_ / 128), 256, 0, stream>>>(
                    xbf + (size_t)t0 * B_ * F_, F_, kT, F_, nullptr, 0, nullptr, 0,
                    nullptr, 0, bias, ZX, G4, nullptr, 0);
                for (int t = t0; t < t0 + nc; ++t) {
                    gemm2<64, 128, 1, 0, 0, 0><<<gz, 256, 0, stream>>>(
                        H, U_, rT, U_, nullptr, 0, nullptr, 0,
                        ZX + (size_t)(t - t0) * B_ * G4, G4, nullptr, z, G4, nullptr, 0);
                    lstm_pw<<<B_ * U_ / 4 / 256, 256, 0, stream>>>(z, c, H);
                }
            }
        } else {
            for (int t = 0; t < T_; ++t) {
                gemm2<64, 128, 0, 1, 1, 0><<<gz, 256, 0, stream>>>(
                    xbf + (size_t)t * B_ * F_, F_, kT, F_, H, U_, rT, U_,
                    nullptr, 0, bias, z, G4, nullptr, 0);
                lstm_pw<<<B_ * U_ / 4 / 256, 256, 0, stream>>>(z, c, H);
            }
        }
        for (int t = 1; t < OT; ++t) {
            gemm2<64, 128, 0, 0, 1, 0><<<gz, 256, 0, stream>>>(
                H + (size_t)(t - 1) * SLOT, U_, WcT, U_, nullptr, 0, nullptr, 0,
                nullptr, 0, bc, z, G4, nullptr, 0);
            lstm_pw<<<B_ * U_ / 4 / 256, 256, 0, stream>>>(z, c, H + (size_t)t * SLOT);
        }
        gemm2<128, 128, 0, 0, 1, 2><<<dim3(F_ / 128, OT * B_ / 128), 256, 0, stream>>>(
            H, U_, dT, U_, nullptr, 0, nullptr, 0, nullptr, 0, bd, out, F_, nullptr, 0);
    } else {
        // Fallback (~101 MB): per-step everything.
        u16* kT = (u16*)alloc(szKT);
        u16* rT = (u16*)alloc(szRT);
        u16* dT = (u16*)alloc(szDT);
        float* z = (float*)alloc(szZ);
        float* c = (float*)alloc(szC);
        u16* h = (u16*)alloc(szPred);
        u16* pred = (u16*)alloc(szPred);

        cvt_x_tmajor<<<(B_ * T_ * F_ / 4 + 255) / 256, 256, 0, stream>>>(x, xbf);
        transpose_f32_bf16<<<dim3(G4 / 32, F_ / 32), tb32, 0, stream>>>(Wk, kT, F_, G4);
        transpose_f32_bf16<<<dim3(G4 / 32, U_ / 32), tb32, 0, stream>>>(Wr, rT, U_, G4);
        transpose_f32_bf16<<<dim3(F_ / 32, U_ / 32), tb32, 0, stream>>>(Wd, dT, U_, F_);
        hipMemsetAsync(c, 0, szC, stream);
        hipMemsetAsync(h, 0, szPred, stream);

        for (int t = 0; t < T_; ++t) {
            gemm2<64, 128, 0, 1, 1, 0><<<gz, 256, 0, stream>>>(
                xbf + (size_t)t * B_ * F_, F_, kT, F_, h, U_, rT, U_,
                nullptr, 0, bias, z, G4, nullptr, 0);
            lstm_pw<<<B_ * U_ / 4 / 256, 256, 0, stream>>>(z, c, h);
        }
        gemm2<64, 128, 0, 0, 1, 3><<<dim3(F_ / 128, B_ / 64), 256, 0, stream>>>(
            h, U_, dT, U_, nullptr, 0, nullptr, 0, nullptr, 0, bd,
            out, (long)OT * F_, pred, U_);
        for (int t = 1; t < OT; ++t) {
            gemm2<64, 128, 0, 1, 1, 0><<<gz, 256, 0, stream>>>(
                pred, U_, kT, F_, h, U_, rT, U_, nullptr, 0, bias, z, G4, nullptr, 0);
            lstm_pw<<<B_ * U_ / 4 / 256, 256, 0, stream>>>(z, c, h);
            gemm2<64, 128, 0, 0, 1, 3><<<dim3(F_ / 128, B_ / 64), 256, 0, stream>>>(
                h, U_, dT, U_, nullptr, 0, nullptr, 0, nullptr, 0, bd,
                out + (size_t)t * F_, (long)OT * F_, pred, U_);
        }
    }
}

// Round 5
// 4655.806 us; speedup vs baseline: 2.0023x; 1.1437x over previous
//
#include <hip/hip_runtime.h>
#include <hip/hip_bf16.h>
#include <cstddef>
#include <cstdint>

typedef __attribute__((ext_vector_type(8))) short short8;
typedef __attribute__((ext_vector_type(4))) float f32x4;
typedef unsigned short u16;
typedef unsigned int u32;

#define B_ 512
#define T_ 48
#define F_ 2048
#define U_ 2048
#define G4 8192
#define OT 24

__device__ __forceinline__ u16 f2bf(float f) {
    __hip_bfloat16 b = __float2bfloat16(f);
    return *reinterpret_cast<u16*>(&b);
}
__device__ __forceinline__ float bf2f(u16 v) {
    union { u32 u; float f; } c;
    c.u = ((u32)v) << 16;
    return c.f;
}

__device__ __forceinline__ void gl_lds16(const void* g, void* l) {
    __builtin_amdgcn_global_load_lds(
        (const __attribute__((address_space(1))) void*)g,
        (__attribute__((address_space(3))) void*)l, 16, 0, 0);
}

// ---------------------------------------------------------------------------
// fp32 [R][C] -> bf16 [C][R]; ILV=1 permutes output rows to gate-interleaved
// n' = (u<<2)|g where input col c = g*2048 + u.
// ---------------------------------------------------------------------------
template <int ILV>
__global__ void transpose_f32_bf16(const float* __restrict__ in,
                                   u16* __restrict__ out, int R, int C) {
    __shared__ float tile[32][33];
    int bx = blockIdx.x * 32;
    int by = blockIdx.y * 32;
    int tx = threadIdx.x, ty = threadIdx.y;
#pragma unroll
    for (int j = 0; j < 32; j += 8)
        tile[ty + j][tx] = in[(size_t)(by + ty + j) * C + bx + tx];
    __syncthreads();
#pragma unroll
    for (int j = 0; j < 32; j += 8) {
        int cidx = bx + ty + j;
        int orow = ILV ? (((cidx & 2047) << 2) | (cidx >> 11)) : cidx;
        out[(size_t)orow * R + by + tx] = f2bf(tile[tx][ty + j]);
    }
}

// flat fp32 -> bf16
__global__ void cvt_bf16(const float* __restrict__ in, u16* __restrict__ out, long n) {
    long i = ((long)blockIdx.x * blockDim.x + threadIdx.x) * 4;
    if (i >= n) return;
    f32x4 v = *(const f32x4*)(in + i);
    ushort4 o;
    o.x = f2bf(v[0]); o.y = f2bf(v[1]); o.z = f2bf(v[2]); o.w = f2bf(v[3]);
    *(ushort4*)(out + i) = o;
}

// x [b][t][f] fp32 -> xbf [t][b][f] bf16
__global__ void cvt_x_tmajor(const float* __restrict__ x, u16* __restrict__ xbf) {
    long i = ((long)blockIdx.x * blockDim.x + threadIdx.x) * 4;
    int f = (int)(i & (F_ - 1));
    long bt = i >> 11;
    int t = (int)(bt % T_);
    int b = (int)(bt / T_);
    f32x4 v = *(const f32x4*)(x + i);
    ushort4 o;
    o.x = f2bf(v[0]); o.y = f2bf(v[1]); o.z = f2bf(v[2]); o.w = f2bf(v[3]);
    *(ushort4*)(xbf + ((size_t)t * B_ + b) * F_ + f) = o;
}

// bias4[n'] = bias[g*2048+u]
__global__ void make_bias4(const float* __restrict__ bias, float* __restrict__ b4) {
    int n = blockIdx.x * 256 + threadIdx.x;
    int g = n & 3, u = n >> 2;
    b4[n] = bias[g * 2048 + u];
}

// bc4[n'] = bias4[n'] + dot(bd, W4kT[n'])
__global__ void bcomb_k(const u16* __restrict__ W4kT, const float* __restrict__ bd,
                        const float* __restrict__ bias4, float* __restrict__ bc) {
    int lane = threadIdx.x & 63, wid = threadIdx.x >> 6;
    int n = blockIdx.x * 4 + wid;
    const u16* row = W4kT + (size_t)n * U_;
    float s = 0.f;
    for (int j0 = lane * 8; j0 < U_; j0 += 512) {
        short8 v = *(const short8*)&row[j0];
#pragma unroll
        for (int e = 0; e < 8; ++e) s += bd[j0 + e] * bf2f((u16)v[e]);
    }
#pragma unroll
    for (int o = 32; o; o >>= 1) s += __shfl_down(s, o);
    if (lane == 0) bc[n] = bias4[n] + s;
}

// ---------------------------------------------------------------------------
// 2-phase double-buffered GEMM pass. A [M,K] bf16 (lda), B^T [N,K] bf16.
// ---------------------------------------------------------------------------
template <int BM, int BN>
__device__ __forceinline__ void gpass(const u16* __restrict__ A, long lda,
                                      const u16* __restrict__ B, int K,
                                      int m0, int n0, int tid,
                                      u16* As, u16* Bs,
                                      f32x4 (&acc)[BM / 32][BN / 32]) {
    const int lane = tid & 63, wid = tid >> 6;
    const int wr = wid >> 1, wc = wid & 1;
    const int r16 = lane & 15, kg = lane >> 4;
    constexpr int MF = BM / 32, NF = BN / 32;
    constexpr int AIS = (BM * 64) / 4096, BIS = (BN * 64) / 4096;
    constexpr int ABUF = BM * 32, BBUF = BN * 32;
    const int lrow = lane >> 2;
    const int ke = (lane & 3) * 8;
    const u16* Ab = A + (size_t)m0 * lda + ke;
    const u16* Bb = B + (size_t)n0 * (size_t)K + ke;

    auto stage = [&](int kt, int buf) {
#pragma unroll
        for (int i = 0; i < AIS; ++i) {
            int row = i * 64 + wid * 16 + lrow;
            gl_lds16(Ab + (size_t)row * lda + kt,
                     As + buf * ABUF + (i * 4096 + wid * 1024) / 2);
        }
#pragma unroll
        for (int i = 0; i < BIS; ++i) {
            int row = i * 64 + wid * 16 + lrow;
            gl_lds16(Bb + (size_t)row * (size_t)K + kt,
                     Bs + buf * BBUF + (i * 4096 + wid * 1024) / 2);
        }
    };
    auto compute = [&](int buf) {
        short8 af[MF], bfv[NF];
#pragma unroll
        for (int mi = 0; mi < MF; ++mi)
            af[mi] = *(const short8*)&As[buf * ABUF + (wr * (BM / 2) + mi * 16 + r16) * 32 + kg * 8];
#pragma unroll
        for (int ni = 0; ni < NF; ++ni)
            bfv[ni] = *(const short8*)&Bs[buf * BBUF + (wc * (BN / 2) + ni * 16 + r16) * 32 + kg * 8];
        __builtin_amdgcn_s_setprio(1);
#pragma unroll
        for (int mi = 0; mi < MF; ++mi)
#pragma unroll
            for (int ni = 0; ni < NF; ++ni)
                acc[mi][ni] = __builtin_amdgcn_mfma_f32_16x16x32_bf16(
                    af[mi], bfv[ni], acc[mi][ni], 0, 0, 0);
        __builtin_amdgcn_s_setprio(0);
    };

    __syncthreads();
    stage(0, 0);
    __syncthreads();
    int cur = 0;
    for (int kt = 32; kt < K; kt += 32) {
        stage(kt, cur ^ 1);
        compute(cur);
        __syncthreads();
        cur ^= 1;
    }
    compute(cur);
}

// CM: 0 none, 1 fp32 Cinit, 2 bf16 Cinit. OUTM: 0 fp32, 1 bf16,
// 2 fp32 with (t,b) remap, 3 fp32 + bf16 secondary.
template <int BM, int BN, int CM, int HAS2, int BIAS, int OUTM>
__global__ __launch_bounds__(256) void gemm2(
    const u16* __restrict__ A1, long lda1, const u16* __restrict__ B1, int K1,
    const u16* __restrict__ A2, long lda2, const u16* __restrict__ B2, int K2,
    const void* __restrict__ Ci, long ldci, const float* __restrict__ bias,
    void* __restrict__ Co, long ldc, void* __restrict__ Co2, long ldc2) {
    __shared__ __align__(16) u16 As[2 * BM * 32];
    __shared__ __align__(16) u16 Bs[2 * BN * 32];
    const int gx = gridDim.x;
    const int nwg = gx * gridDim.y;
    int lin = blockIdx.y * gx + blockIdx.x;
    if ((nwg & 7) == 0) {
        int q = nwg >> 3;
        lin = (lin & 7) * q + (lin >> 3);
    }
    const int m0 = (lin / gx) * BM, n0 = (lin % gx) * BN;
    const int tid = threadIdx.x;

    f32x4 acc[BM / 32][BN / 32] = {};
    gpass<BM, BN>(A1, lda1, B1, K1, m0, n0, tid, As, Bs, acc);
    if constexpr (HAS2) gpass<BM, BN>(A2, lda2, B2, K2, m0, n0, tid, As, Bs, acc);

    const int lane = tid & 63, wid = tid >> 6;
    const int wr = wid >> 1, wc = wid & 1, r16 = lane & 15, rg = lane >> 4;
#pragma unroll
    for (int ni = 0; ni < BN / 32; ++ni) {
        int col = n0 + wc * (BN / 2) + ni * 16 + r16;
        float bv = BIAS ? bias[col] : 0.f;
#pragma unroll
        for (int mi = 0; mi < BM / 32; ++mi) {
#pragma unroll
            for (int r = 0; r < 4; ++r) {
                int row = m0 + wr * (BM / 2) + mi * 16 + rg * 4 + r;
                float v = acc[mi][ni][r] + bv;
                if constexpr (CM == 1) v += ((const float*)Ci)[(size_t)row * ldci + col];
                if constexpr (CM == 2) v += bf2f(((const u16*)Ci)[(size_t)row * ldci + col]);
                if constexpr (OUTM == 0) ((float*)Co)[(size_t)row * ldc + col] = v;
                if constexpr (OUTM == 1) ((u16*)Co)[(size_t)row * ldc + col] = f2bf(v);
                if constexpr (OUTM == 2) {
                    int t = row >> 9, b = row & 511;
                    ((float*)Co)[((size_t)b * OT + t) * F_ + col] = v;
                }
                if constexpr (OUTM == 3) {
                    ((float*)Co)[(size_t)row * ldc + col] = v;
                    ((u16*)Co2)[(size_t)row * ldc2 + col] = f2bf(v);
                }
            }
        }
    }
}

// ---------------------------------------------------------------------------
// Fused LSTM step. Weights gate-interleaved: B row n' = (u<<2)|gate.
// z = A1@B1 [+ A2@B2]; then + (WARM==1 ? zx_bf16 : bc4); gates -> c, hout.
// Grid (64, 8), block 256. BM=64, BN=128 (= 32 u-cols x 4 gates).
// WARM: 0 decode (+bc4), 1 warmup with hoisted zx, 2 fallback dual-GEMM (+bc4).
// ---------------------------------------------------------------------------
template <int WARM>
__global__ __launch_bounds__(256) void lstm_step(
    const u16* __restrict__ A1, long lda1, const u16* __restrict__ B1,
    const u16* __restrict__ A2, long lda2, const u16* __restrict__ B2,
    const u16* __restrict__ zx, const float* __restrict__ bc4,
    float* __restrict__ c, u16* __restrict__ hout) {
    constexpr int BM = 64, BN = 128;
    __shared__ __align__(16) char smem[64 * 132 * 4];  // 33.8 KB, aliased
    u16* As = (u16*)smem;                   // 2*64*32*2  = 8 KB
    u16* Bs = (u16*)(smem + 2 * BM * 32 * 2);  // 2*128*32*2 = 16 KB
    float* zt = (float*)smem;               // 64 x 132 fp32

    const int gx = gridDim.x;
    int lin = blockIdx.y * gx + blockIdx.x;
    const int nwg = gx * gridDim.y;  // 512
    {
        int q = nwg >> 3;
        lin = (lin & 7) * q + (lin >> 3);
    }
    const int m0 = (lin / gx) * BM, n0 = (lin % gx) * BN;
    const int tid = threadIdx.x;

    f32x4 acc[2][4] = {};
    gpass<BM, BN>(A1, lda1, B1, U_, m0, n0, tid, As, Bs, acc);
    if constexpr (WARM == 2) gpass<BM, BN>(A2, lda2, B2, U_, m0, n0, tid, As, Bs, acc);

    // exchange accumulator through LDS so each thread gets all 4 gates of a u
    __syncthreads();
    {
        const int lane = tid & 63, wid = tid >> 6;
        const int wr = wid >> 1, wc = wid & 1, r16 = lane & 15, rg = lane >> 4;
#pragma unroll
        for (int mi = 0; mi < 2; ++mi)
#pragma unroll
            for (int ni = 0; ni < 4; ++ni)
#pragma unroll
                for (int r = 0; r < 4; ++r)
                    zt[(wr * 32 + mi * 16 + rg * 4 + r) * 132 + wc * 64 + ni * 16 + r16] =
                        acc[mi][ni][r];
    }
    __syncthreads();

    const int row = tid >> 5, ul = tid & 31;
    const int ug = (n0 >> 2) + ul;  // global u
#pragma unroll
    for (int j = 0; j < 8; ++j) {
        int rr = j * 8 + row;
        f32x4 zv = *(const f32x4*)&zt[rr * 132 + 4 * ul];
        float zi = zv[0], zf = zv[1], zg = zv[2], zo = zv[3];
        if constexpr (WARM == 1) {
            ushort4 zb = *(const ushort4*)&zx[(size_t)(m0 + rr) * G4 + n0 + 4 * ul];
            zi += bf2f(zb.x); zf += bf2f(zb.y); zg += bf2f(zb.z); zo += bf2f(zb.w);
        } else {
            f32x4 bv = *(const f32x4*)&bc4[n0 + 4 * ul];
            zi += bv[0]; zf += bv[1]; zg += bv[2]; zo += bv[3];
        }
        size_t ci = (size_t)(m0 + rr) * U_ + ug;
        float si = 1.f / (1.f + __expf(-zi));
        float sf = 1.f / (1.f + __expf(-zf));
        float so = 1.f / (1.f + __expf(-zo));
        float cc = sf * c[ci] + si * tanhf(zg);
        c[ci] = cc;
        hout[ci] = f2bf(so * tanhf(cc));
    }
}

// ---------------------------------------------------------------------------
extern "C" void kernel_launch(void* const* d_in, const int* in_sizes, int n_in,
                              void* d_out, int out_size, void* d_ws, size_t ws_size,
                              hipStream_t stream) {
    const float* x = (const float*)d_in[0];
    const float* Wk = (const float*)d_in[1];
    const float* Wr = (const float*)d_in[2];
    const float* bias = (const float*)d_in[3];
    const float* Wd = (const float*)d_in[4];
    const float* bd = (const float*)d_in[5];
    float* out = (float*)d_out;

    // d_out doubles as bf16-x storage (t-major): dead until the final pred GEMM.
    u16* xbf = (u16*)d_out;

    auto pad = [](size_t s) { return (s + 255) & ~(size_t)255; };
    const size_t szW4 = (size_t)G4 * U_ * 2;      // 32 MB
    const size_t szDT = (size_t)U_ * F_ * 2;      // 8 MB
    const size_t szB4 = (size_t)G4 * 4;           // 32 KB
    const size_t szH = (size_t)OT * B_ * U_ * 2;  // 48 MB
    const size_t szHP = (size_t)B_ * U_ * 2;      // 2 MB
    const size_t szC = (size_t)B_ * U_ * 4;       // 4 MB
    const size_t szZX1 = (size_t)B_ * G4 * 2;     // 8.39 MB / step (bf16)
    const size_t SLOT = (size_t)B_ * U_;

    const size_t needMain = pad(szW4) * 3 + pad(szDT) * 2 + pad(szB4) * 2 +
                            pad(szH) + pad(szHP) * 2 + pad(szC) + pad(szZX1);
    const int path = ws_size >= needMain ? 1 : 0;

    char* p = (char*)d_ws;
    auto alloc = [&](size_t bytes) { void* r = p; p += (bytes + 255) & ~(size_t)255; return r; };

    dim3 tb32(32, 8);
    const dim3 gstep(64, 8);  // fused step grid

    if (path == 1) {
        u16* W4kT = (u16*)alloc(szW4);
        u16* W4rT = (u16*)alloc(szW4);
        u16* W4cT = (u16*)alloc(szW4);
        u16* dT = (u16*)alloc(szDT);
        u16* dbf = (u16*)alloc(szDT);
        float* bias4 = (float*)alloc(szB4);
        float* bc4 = (float*)alloc(szB4);
        u16* H = (u16*)alloc(szH);
        u16* hp0 = (u16*)alloc(szHP);
        u16* hp1 = (u16*)alloc(szHP);
        float* c = (float*)alloc(szC);

        size_t avail = ws_size - (size_t)(p - (char*)d_ws);
        int chunk = (int)(avail / szZX1);
        if (chunk > T_) chunk = T_;
        u16* ZX = (u16*)alloc((size_t)chunk * szZX1);

        cvt_x_tmajor<<<(B_ * T_ * F_ / 4 + 255) / 256, 256, 0, stream>>>(x, xbf);
        transpose_f32_bf16<1><<<dim3(G4 / 32, F_ / 32), tb32, 0, stream>>>(Wk, W4kT, F_, G4);
        transpose_f32_bf16<1><<<dim3(G4 / 32, U_ / 32), tb32, 0, stream>>>(Wr, W4rT, U_, G4);
        transpose_f32_bf16<0><<<dim3(F_ / 32, U_ / 32), tb32, 0, stream>>>(Wd, dT, U_, F_);
        cvt_bf16<<<(U_ * F_ / 4 + 255) / 256, 256, 0, stream>>>(Wd, dbf, (long)U_ * F_);
        make_bias4<<<G4 / 256, 256, 0, stream>>>(bias, bias4);
        bcomb_k<<<G4 / 4, 256, 0, stream>>>(W4kT, bd, bias4, bc4);

        // W4cT[n'][k] = W4rT[n'][k] + sum_j W4kT[n'][j] * Wd[k][j]
        gemm2<128, 128, 2, 0, 0, 1><<<dim3(U_ / 128, G4 / 128), 256, 0, stream>>>(
            W4kT, U_, dbf, F_, nullptr, 0, nullptr, 0, W4rT, U_, nullptr,
            W4cT, U_, nullptr, 0);

        hipMemsetAsync(c, 0, szC, stream);
        hipMemsetAsync(hp0, 0, szHP, stream);

        for (int t0 = 0; t0 < T_; t0 += chunk) {
            int nc = chunk < T_ - t0 ? chunk : T_ - t0;
            // ZX[tt] = x_tt @ W4kT + bias4  (bf16, interleaved cols)
            gemm2<128, 128, 0, 0, 1, 1><<<dim3(G4 / 128, nc * B_ / 128), 256, 0, stream>>>(
                xbf + (size_t)t0 * B_ * F_, F_, W4kT, F_, nullptr, 0, nullptr, 0,
                nullptr, 0, bias4, ZX, G4, nullptr, 0);
            for (int t = t0; t < t0 + nc; ++t) {
                const u16* hin = (t & 1) ? hp1 : hp0;
                u16* hout = (t == T_ - 1) ? H : ((t & 1) ? hp0 : hp1);
                lstm_step<1><<<gstep, 256, 0, stream>>>(
                    hin, U_, W4rT, nullptr, 0, nullptr,
                    ZX + (size_t)(t - t0) * B_ * G4, nullptr, c, hout);
            }
        }
        for (int t = 1; t < OT; ++t) {
            lstm_step<0><<<gstep, 256, 0, stream>>>(
                H + (size_t)(t - 1) * SLOT, U_, W4cT, nullptr, 0, nullptr,
                nullptr, bc4, c, H + (size_t)t * SLOT);
        }
        // out[b][t][f] = H[t][b] @ Wd + bd
        gemm2<128, 128, 0, 0, 1, 2><<<dim3(F_ / 128, OT * B_ / 128), 256, 0, stream>>>(
            H, U_, dT, U_, nullptr, 0, nullptr, 0, nullptr, 0, bd, out, F_, nullptr, 0);
    } else {
        // Fallback (~82 MB): no ZX hoist, no Wcomb, per-step pred GEMM.
        u16* W4kT = (u16*)alloc(szW4);
        u16* W4rT = (u16*)alloc(szW4);
        u16* dT = (u16*)alloc(szDT);
        float* bias4 = (float*)alloc(szB4);
        u16* hp0 = (u16*)alloc(szHP);
        u16* hp1 = (u16*)alloc(szHP);
        u16* pred = (u16*)alloc(szHP);
        float* c = (float*)alloc(szC);

        cvt_x_tmajor<<<(B_ * T_ * F_ / 4 + 255) / 256, 256, 0, stream>>>(x, xbf);
        transpose_f32_bf16<1><<<dim3(G4 / 32, F_ / 32), tb32, 0, stream>>>(Wk, W4kT, F_, G4);
        transpose_f32_bf16<1><<<dim3(G4 / 32, U_ / 32), tb32, 0, stream>>>(Wr, W4rT, U_, G4);
        transpose_f32_bf16<0><<<dim3(F_ / 32, U_ / 32), tb32, 0, stream>>>(Wd, dT, U_, F_);
        make_bias4<<<G4 / 256, 256, 0, stream>>>(bias, bias4);
        hipMemsetAsync(c, 0, szC, stream);
        hipMemsetAsync(hp0, 0, szHP, stream);

        u16* hin = hp0;
        u16* hout = hp1;
        for (int t = 0; t < T_; ++t) {
            lstm_step<2><<<gstep, 256, 0, stream>>>(
                hin, U_, W4rT, xbf + (size_t)t * B_ * F_, F_, W4kT,
                nullptr, bias4, c, hout);
            u16* tmp = hin; hin = hout; hout = tmp;
        }
        gemm2<64, 128, 0, 0, 1, 3><<<dim3(F_ / 128, B_ / 64), 256, 0, stream>>>(
            hin, U_, dT, U_, nullptr, 0, nullptr, 0, nullptr, 0, bd,
            out, (long)OT * F_, pred, U_);
        for (int t = 1; t < OT; ++t) {
            lstm_step<2><<<gstep, 256, 0, stream>>>(
                hin, U_, W4rT, pred, U_, W4kT, nullptr, bias4, c, hout);
            u16* tmp = hin; hin = hout; hout = tmp;
            gemm2<64, 128, 0, 0, 1, 3><<<dim3(F_ / 128, B_ / 64), 256, 0, stream>>>(
                hin, U_, dT, U_, nullptr, 0, nullptr, 0, nullptr, 0, bd,
                out + (size_t)t * F_, (long)OT * F_, pred, U_);
        }
    }
}

// Round 6
// 3237.612 us; speedup vs baseline: 2.8794x; 1.4380x over previous
//
#include <hip/hip_runtime.h>
#include <hip/hip_bf16.h>
#include <cstddef>
#include <cstdint>

typedef __attribute__((ext_vector_type(8))) short short8;
typedef __attribute__((ext_vector_type(4))) float f32x4;
typedef unsigned short u16;
typedef unsigned int u32;

#define B_ 512
#define T_ 48
#define F_ 2048
#define U_ 2048
#define G4 8192
#define OT 24

__device__ __forceinline__ u16 f2bf(float f) {
    __hip_bfloat16 b = __float2bfloat16(f);
    return *reinterpret_cast<u16*>(&b);
}
__device__ __forceinline__ float bf2f(u16 v) {
    union { u32 u; float f; } c;
    c.u = ((u32)v) << 16;
    return c.f;
}

__device__ __forceinline__ void gl_lds16(const void* g, void* l) {
    __builtin_amdgcn_global_load_lds(
        (const __attribute__((address_space(1))) void*)g,
        (__attribute__((address_space(3))) void*)l, 16, 0, 0);
}

// ---------------------------------------------------------------------------
// XCD/L2-aware tile mapping: per-XCD n-slab (gx/8 n-tiles), 4x4 epoch walk
// inside the slab so the B-band (<=2MB) stays L2-resident while A streams.
// Falls back to plain bijective XCD swizzle when shapes don't divide.
// ---------------------------------------------------------------------------
__device__ __forceinline__ void map_tile(int BM, int BN, int& m0, int& n0) {
    const int gx = gridDim.x, gy = gridDim.y;
    int lin = blockIdx.y * gx + blockIdx.x;
    const int nwg = gx * gy;
    const int sn = gx >> 3;
    const int EN = (sn >= 4) ? 4 : sn;
    const int EM = 4;
    bool ok = ((gx & 7) == 0) && ((gy & 3) == 0) && (sn < 4 || (sn & 3) == 0);
    if (ok) {
        int xcd = lin & 7, idx = lin >> 3;
        int epw = EM * EN;
        int e = idx / epw, r = idx % epw;
        int meb = gy / EM;  // epochs per n-band
        int ne = e / meb, me = e % meb;
        int mi = r % EM, nli = r / EM;
        int m = me * EM + mi;
        int nl = ne * EN + nli;
        m0 = m * BM;
        n0 = (xcd * sn + nl) * BN;
    } else {
        if ((nwg & 7) == 0) {
            int q = nwg >> 3;
            lin = (lin & 7) * q + (lin >> 3);
        }
        m0 = (lin / gx) * BM;
        n0 = (lin % gx) * BN;
    }
}

// ---------------------------------------------------------------------------
// fp32 [R][C] -> bf16 [C][R]; ILV=1 permutes output rows to gate-interleaved
// n' = (u<<2)|g where input col c = g*2048 + u.
// ---------------------------------------------------------------------------
template <int ILV>
__global__ void transpose_f32_bf16(const float* __restrict__ in,
                                   u16* __restrict__ out, int R, int C) {
    __shared__ float tile[32][33];
    int bx = blockIdx.x * 32;
    int by = blockIdx.y * 32;
    int tx = threadIdx.x, ty = threadIdx.y;
#pragma unroll
    for (int j = 0; j < 32; j += 8)
        tile[ty + j][tx] = in[(size_t)(by + ty + j) * C + bx + tx];
    __syncthreads();
#pragma unroll
    for (int j = 0; j < 32; j += 8) {
        int cidx = bx + ty + j;
        int orow = ILV ? (((cidx & 2047) << 2) | (cidx >> 11)) : cidx;
        out[(size_t)orow * R + by + tx] = f2bf(tile[tx][ty + j]);
    }
}

// flat fp32 -> bf16
__global__ void cvt_bf16(const float* __restrict__ in, u16* __restrict__ out, long n) {
    long i = ((long)blockIdx.x * blockDim.x + threadIdx.x) * 4;
    if (i >= n) return;
    f32x4 v = *(const f32x4*)(in + i);
    ushort4 o;
    o.x = f2bf(v[0]); o.y = f2bf(v[1]); o.z = f2bf(v[2]); o.w = f2bf(v[3]);
    *(ushort4*)(out + i) = o;
}

// x [b][t][f] fp32 -> xbf [t][b][f] bf16
__global__ void cvt_x_tmajor(const float* __restrict__ x, u16* __restrict__ xbf) {
    long i = ((long)blockIdx.x * blockDim.x + threadIdx.x) * 4;
    int f = (int)(i & (F_ - 1));
    long bt = i >> 11;
    int t = (int)(bt % T_);
    int b = (int)(bt / T_);
    f32x4 v = *(const f32x4*)(x + i);
    ushort4 o;
    o.x = f2bf(v[0]); o.y = f2bf(v[1]); o.z = f2bf(v[2]); o.w = f2bf(v[3]);
    *(ushort4*)(xbf + ((size_t)t * B_ + b) * F_ + f) = o;
}

// bias4[n'] = bias[g*2048+u]
__global__ void make_bias4(const float* __restrict__ bias, float* __restrict__ b4) {
    int n = blockIdx.x * 256 + threadIdx.x;
    int g = n & 3, u = n >> 2;
    b4[n] = bias[g * 2048 + u];
}

// bc4[n'] = bias4[n'] + dot(bd, W4kT[n'])
__global__ void bcomb_k(const u16* __restrict__ W4kT, const float* __restrict__ bd,
                        const float* __restrict__ bias4, float* __restrict__ bc) {
    int lane = threadIdx.x & 63, wid = threadIdx.x >> 6;
    int n = blockIdx.x * 4 + wid;
    const u16* row = W4kT + (size_t)n * U_;
    float s = 0.f;
    for (int j0 = lane * 8; j0 < U_; j0 += 512) {
        short8 v = *(const short8*)&row[j0];
#pragma unroll
        for (int e = 0; e < 8; ++e) s += bd[j0 + e] * bf2f((u16)v[e]);
    }
#pragma unroll
    for (int o = 32; o; o >>= 1) s += __shfl_down(s, o);
    if (lane == 0) bc[n] = bias4[n] + s;
}

// ---------------------------------------------------------------------------
// 2-phase double-buffered GEMM pass with both-sides LDS XOR swizzle:
// linear global_load_lds dest + inverse-swizzled GLOBAL source slot +
// swizzled ds_read address (m173/m201 pattern). A [M,K] bf16 (lda),
// B^T [N,K] bf16 (ldb=K). K % BK == 0.
// ---------------------------------------------------------------------------
template <int BM, int BN, int BK>
__device__ __forceinline__ void gpass(const u16* __restrict__ A, long lda,
                                      const u16* __restrict__ B, int K,
                                      int m0, int n0, int tid,
                                      u16* As, u16* Bs,
                                      f32x4 (&acc)[BM / 32][BN / 32]) {
    const int lane = tid & 63, wid = tid >> 6;
    const int wr = wid >> 1, wc = wid & 1;
    const int r16 = lane & 15, kg = lane >> 4;
    constexpr int MF = BM / 32, NF = BN / 32;
    constexpr int S = BK / 8;        // 16B slots per row
    constexpr int RPI = 64 / S;      // rows per wave-instr (1 KiB)
    constexpr int AIS = BM / RPI / 4;
    constexpr int BIS = BN / RPI / 4;
    constexpr int ABUF = BM * BK, BBUF = BN * BK;
    const int rl = lane / S;             // row within instr chunk
    const int sl = lane % S;             // lane's LDS slot within row
    const int sw = (sl ^ (rl & (S - 1))) * 8;  // swizzled global slot (elems)

    auto stage = [&](int kt, int buf) {
#pragma unroll
        for (int i = 0; i < AIS; ++i) {
            int chunk = wid * AIS + i;
            gl_lds16(A + (size_t)(m0 + chunk * RPI + rl) * lda + kt + sw,
                     As + buf * ABUF + chunk * RPI * BK);
        }
#pragma unroll
        for (int i = 0; i < BIS; ++i) {
            int chunk = wid * BIS + i;
            gl_lds16(B + (size_t)(n0 + chunk * RPI + rl) * (size_t)K + kt + sw,
                     Bs + buf * BBUF + chunk * RPI * BK);
        }
    };
    auto compute = [&](int buf) {
        __builtin_amdgcn_s_setprio(1);
#pragma unroll
        for (int ks = 0; ks < BK / 32; ++ks) {
            short8 af[MF], bfv[NF];
#pragma unroll
            for (int mi = 0; mi < MF; ++mi) {
                int row = wr * (BM / 2) + mi * 16 + r16;
                int s = (ks * 4 + kg) ^ (row & (S - 1));
                af[mi] = *(const short8*)&As[buf * ABUF + row * BK + s * 8];
            }
#pragma unroll
            for (int ni = 0; ni < NF; ++ni) {
                int row = wc * (BN / 2) + ni * 16 + r16;
                int s = (ks * 4 + kg) ^ (row & (S - 1));
                bfv[ni] = *(const short8*)&Bs[buf * BBUF + row * BK + s * 8];
            }
#pragma unroll
            for (int mi = 0; mi < MF; ++mi)
#pragma unroll
                for (int ni = 0; ni < NF; ++ni)
                    acc[mi][ni] = __builtin_amdgcn_mfma_f32_16x16x32_bf16(
                        af[mi], bfv[ni], acc[mi][ni], 0, 0, 0);
        }
        __builtin_amdgcn_s_setprio(0);
    };

    __syncthreads();
    stage(0, 0);
    __syncthreads();
    int cur = 0;
    for (int kt = BK; kt < K; kt += BK) {
        stage(kt, cur ^ 1);
        compute(cur);
        __syncthreads();
        cur ^= 1;
    }
    compute(cur);
}

// CM: 0 none, 1 fp32 Cinit, 2 bf16 Cinit. OUTM: 0 fp32, 1 bf16,
// 2 fp32 with (t,b) remap, 3 fp32 + bf16 secondary.
template <int BM, int BN, int CM, int HAS2, int BIAS, int OUTM>
__global__ __launch_bounds__(256) void gemm2(
    const u16* __restrict__ A1, long lda1, const u16* __restrict__ B1, int K1,
    const u16* __restrict__ A2, long lda2, const u16* __restrict__ B2, int K2,
    const void* __restrict__ Ci, long ldci, const float* __restrict__ bias,
    void* __restrict__ Co, long ldc, void* __restrict__ Co2, long ldc2) {
    __shared__ __align__(16) u16 As[2 * BM * 32];
    __shared__ __align__(16) u16 Bs[2 * BN * 32];
    int m0, n0;
    map_tile(BM, BN, m0, n0);
    const int tid = threadIdx.x;

    f32x4 acc[BM / 32][BN / 32] = {};
    gpass<BM, BN, 32>(A1, lda1, B1, K1, m0, n0, tid, As, Bs, acc);
    if constexpr (HAS2) gpass<BM, BN, 32>(A2, lda2, B2, K2, m0, n0, tid, As, Bs, acc);

    const int lane = tid & 63, wid = tid >> 6;
    const int wr = wid >> 1, wc = wid & 1, r16 = lane & 15, rg = lane >> 4;
#pragma unroll
    for (int ni = 0; ni < BN / 32; ++ni) {
        int col = n0 + wc * (BN / 2) + ni * 16 + r16;
        float bv = BIAS ? bias[col] : 0.f;
#pragma unroll
        for (int mi = 0; mi < BM / 32; ++mi) {
#pragma unroll
            for (int r = 0; r < 4; ++r) {
                int row = m0 + wr * (BM / 2) + mi * 16 + rg * 4 + r;
                float v = acc[mi][ni][r] + bv;
                if constexpr (CM == 1) v += ((const float*)Ci)[(size_t)row * ldci + col];
                if constexpr (CM == 2) v += bf2f(((const u16*)Ci)[(size_t)row * ldci + col]);
                if constexpr (OUTM == 0) ((float*)Co)[(size_t)row * ldc + col] = v;
                if constexpr (OUTM == 1) ((u16*)Co)[(size_t)row * ldc + col] = f2bf(v);
                if constexpr (OUTM == 2) {
                    int t = row >> 9, b = row & 511;
                    ((float*)Co)[((size_t)b * OT + t) * F_ + col] = v;
                }
                if constexpr (OUTM == 3) {
                    ((float*)Co)[(size_t)row * ldc + col] = v;
                    ((u16*)Co2)[(size_t)row * ldc2 + col] = f2bf(v);
                }
            }
        }
    }
}

// ---------------------------------------------------------------------------
// Fused LSTM step. Weights gate-interleaved: B row n' = (u<<2)|gate.
// z = A1@B1 [+ A2@B2]; then + (WARM==1 ? zx_bf16 : bc4); gates -> c, hout.
// Grid (64, 8), block 256. BM=64, BN=128, BK=64 (32 K-iters, 16 MFMA/phase).
// WARM: 0 decode (+bc4), 1 warmup with hoisted zx, 2 fallback dual-GEMM (+bc4).
// ---------------------------------------------------------------------------
template <int WARM>
__global__ __launch_bounds__(256) void lstm_step(
    const u16* __restrict__ A1, long lda1, const u16* __restrict__ B1,
    const u16* __restrict__ A2, long lda2, const u16* __restrict__ B2,
    const u16* __restrict__ zx, const float* __restrict__ bc4,
    float* __restrict__ c, u16* __restrict__ hout) {
    constexpr int BM = 64, BN = 128, BK = 64;
    __shared__ __align__(16) char smem[49152];  // 48 KB: GEMM bufs / zt alias
    u16* As = (u16*)smem;                       // 2*64*64*2  = 16 KB
    u16* Bs = (u16*)(smem + 2 * BM * BK * 2);   // 2*128*64*2 = 32 KB
    float* zt = (float*)smem;                   // 64 x 132 fp32 = 33.8 KB

    int m0, n0;
    map_tile(BM, BN, m0, n0);
    const int tid = threadIdx.x;

    f32x4 acc[2][4] = {};
    gpass<BM, BN, BK>(A1, lda1, B1, U_, m0, n0, tid, As, Bs, acc);
    if constexpr (WARM == 2) gpass<BM, BN, BK>(A2, lda2, B2, U_, m0, n0, tid, As, Bs, acc);

    // exchange accumulator through LDS so each thread gets all 4 gates of a u
    __syncthreads();
    {
        const int lane = tid & 63, wid = tid >> 6;
        const int wr = wid >> 1, wc = wid & 1, r16 = lane & 15, rg = lane >> 4;
#pragma unroll
        for (int mi = 0; mi < 2; ++mi)
#pragma unroll
            for (int ni = 0; ni < 4; ++ni)
#pragma unroll
                for (int r = 0; r < 4; ++r)
                    zt[(wr * 32 + mi * 16 + rg * 4 + r) * 132 + wc * 64 + ni * 16 + r16] =
                        acc[mi][ni][r];
    }
    __syncthreads();

    const int row = tid >> 5, ul = tid & 31;
    const int ug = (n0 >> 2) + ul;  // global u
#pragma unroll
    for (int j = 0; j < 8; ++j) {
        int rr = j * 8 + row;
        f32x4 zv = *(const f32x4*)&zt[rr * 132 + 4 * ul];
        float zi = zv[0], zf = zv[1], zg = zv[2], zo = zv[3];
        if constexpr (WARM == 1) {
            ushort4 zb = *(const ushort4*)&zx[(size_t)(m0 + rr) * G4 + n0 + 4 * ul];
            zi += bf2f(zb.x); zf += bf2f(zb.y); zg += bf2f(zb.z); zo += bf2f(zb.w);
        } else {
            f32x4 bv = *(const f32x4*)&bc4[n0 + 4 * ul];
            zi += bv[0]; zf += bv[1]; zg += bv[2]; zo += bv[3];
        }
        size_t ci = (size_t)(m0 + rr) * U_ + ug;
        float si = 1.f / (1.f + __expf(-zi));
        float sf = 1.f / (1.f + __expf(-zf));
        float so = 1.f / (1.f + __expf(-zo));
        float cc = sf * c[ci] + si * tanhf(zg);
        c[ci] = cc;
        hout[ci] = f2bf(so * tanhf(cc));
    }
}

// ---------------------------------------------------------------------------
extern "C" void kernel_launch(void* const* d_in, const int* in_sizes, int n_in,
                              void* d_out, int out_size, void* d_ws, size_t ws_size,
                              hipStream_t stream) {
    const float* x = (const float*)d_in[0];
    const float* Wk = (const float*)d_in[1];
    const float* Wr = (const float*)d_in[2];
    const float* bias = (const float*)d_in[3];
    const float* Wd = (const float*)d_in[4];
    const float* bd = (const float*)d_in[5];
    float* out = (float*)d_out;

    // d_out doubles as bf16-x storage (t-major): dead until the final pred GEMM.
    u16* xbf = (u16*)d_out;

    auto pad = [](size_t s) { return (s + 255) & ~(size_t)255; };
    const size_t szW4 = (size_t)G4 * U_ * 2;      // 32 MB
    const size_t szDT = (size_t)U_ * F_ * 2;      // 8 MB
    const size_t szB4 = (size_t)G4 * 4;           // 32 KB
    const size_t szH = (size_t)OT * B_ * U_ * 2;  // 48 MB
    const size_t szHP = (size_t)B_ * U_ * 2;      // 2 MB
    const size_t szC = (size_t)B_ * U_ * 4;       // 4 MB
    const size_t szZX1 = (size_t)B_ * G4 * 2;     // 8.39 MB / step (bf16)
    const size_t SLOT = (size_t)B_ * U_;

    const size_t needMain = pad(szW4) * 3 + pad(szDT) * 2 + pad(szB4) * 2 +
                            pad(szH) + pad(szHP) * 2 + pad(szC) + pad(szZX1);
    const int path = ws_size >= needMain ? 1 : 0;

    char* p = (char*)d_ws;
    auto alloc = [&](size_t bytes) { void* r = p; p += (bytes + 255) & ~(size_t)255; return r; };

    dim3 tb32(32, 8);
    const dim3 gstep(64, 8);  // fused step grid

    if (path == 1) {
        u16* W4kT = (u16*)alloc(szW4);
        u16* W4rT = (u16*)alloc(szW4);
        u16* W4cT = (u16*)alloc(szW4);
        u16* dT = (u16*)alloc(szDT);
        u16* dbf = (u16*)alloc(szDT);
        float* bias4 = (float*)alloc(szB4);
        float* bc4 = (float*)alloc(szB4);
        u16* H = (u16*)alloc(szH);
        u16* hp0 = (u16*)alloc(szHP);
        u16* hp1 = (u16*)alloc(szHP);
        float* c = (float*)alloc(szC);

        size_t avail = ws_size - (size_t)(p - (char*)d_ws);
        int chunk = (int)(avail / szZX1);
        if (chunk > T_) chunk = T_;
        u16* ZX = (u16*)alloc((size_t)chunk * szZX1);

        cvt_x_tmajor<<<(B_ * T_ * F_ / 4 + 255) / 256, 256, 0, stream>>>(x, xbf);
        transpose_f32_bf16<1><<<dim3(G4 / 32, F_ / 32), tb32, 0, stream>>>(Wk, W4kT, F_, G4);
        transpose_f32_bf16<1><<<dim3(G4 / 32, U_ / 32), tb32, 0, stream>>>(Wr, W4rT, U_, G4);
        transpose_f32_bf16<0><<<dim3(F_ / 32, U_ / 32), tb32, 0, stream>>>(Wd, dT, U_, F_);
        cvt_bf16<<<(U_ * F_ / 4 + 255) / 256, 256, 0, stream>>>(Wd, dbf, (long)U_ * F_);
        make_bias4<<<G4 / 256, 256, 0, stream>>>(bias, bias4);
        bcomb_k<<<G4 / 4, 256, 0, stream>>>(W4kT, bd, bias4, bc4);

        // W4cT[n'][k] = W4rT[n'][k] + sum_j W4kT[n'][j] * Wd[k][j]
        gemm2<128, 128, 2, 0, 0, 1><<<dim3(U_ / 128, G4 / 128), 256, 0, stream>>>(
            W4kT, U_, dbf, F_, nullptr, 0, nullptr, 0, W4rT, U_, nullptr,
            W4cT, U_, nullptr, 0);

        hipMemsetAsync(c, 0, szC, stream);
        hipMemsetAsync(hp0, 0, szHP, stream);

        for (int t0 = 0; t0 < T_; t0 += chunk) {
            int nc = chunk < T_ - t0 ? chunk : T_ - t0;
            // ZX[tt] = x_tt @ W4kT + bias4  (bf16, interleaved cols)
            gemm2<128, 128, 0, 0, 1, 1><<<dim3(G4 / 128, nc * B_ / 128), 256, 0, stream>>>(
                xbf + (size_t)t0 * B_ * F_, F_, W4kT, F_, nullptr, 0, nullptr, 0,
                nullptr, 0, bias4, ZX, G4, nullptr, 0);
            for (int t = t0; t < t0 + nc; ++t) {
                const u16* hin = (t & 1) ? hp1 : hp0;
                u16* hout = (t == T_ - 1) ? H : ((t & 1) ? hp0 : hp1);
                lstm_step<1><<<gstep, 256, 0, stream>>>(
                    hin, U_, W4rT, nullptr, 0, nullptr,
                    ZX + (size_t)(t - t0) * B_ * G4, nullptr, c, hout);
            }
        }
        for (int t = 1; t < OT; ++t) {
            lstm_step<0><<<gstep, 256, 0, stream>>>(
                H + (size_t)(t - 1) * SLOT, U_, W4cT, nullptr, 0, nullptr,
                nullptr, bc4, c, H + (size_t)t * SLOT);
        }
        // out[b][t][f] = H[t][b] @ Wd + bd
        gemm2<128, 128, 0, 0, 1, 2><<<dim3(F_ / 128, OT * B_ / 128), 256, 0, stream>>>(
            H, U_, dT, U_, nullptr, 0, nullptr, 0, nullptr, 0, bd, out, F_, nullptr, 0);
    } else {
        // Fallback (~82 MB): no ZX hoist, no Wcomb, per-step pred GEMM.
        u16* W4kT = (u16*)alloc(szW4);
        u16* W4rT = (u16*)alloc(szW4);
        u16* dT = (u16*)alloc(szDT);
        float* bias4 = (float*)alloc(szB4);
        u16* hp0 = (u16*)alloc(szHP);
        u16* hp1 = (u16*)alloc(szHP);
        u16* pred = (u16*)alloc(szHP);
        float* c = (float*)alloc(szC);

        cvt_x_tmajor<<<(B_ * T_ * F_ / 4 + 255) / 256, 256, 0, stream>>>(x, xbf);
        transpose_f32_bf16<1><<<dim3(G4 / 32, F_ / 32), tb32, 0, stream>>>(Wk, W4kT, F_, G4);
        transpose_f32_bf16<1><<<dim3(G4 / 32, U_ / 32), tb32, 0, stream>>>(Wr, W4rT, U_, G4);
        transpose_f32_bf16<0><<<dim3(F_ / 32, U_ / 32), tb32, 0, stream>>>(Wd, dT, U_, F_);
        make_bias4<<<G4 / 256, 256, 0, stream>>>(bias, bias4);
        hipMemsetAsync(c, 0, szC, stream);
        hipMemsetAsync(hp0, 0, szHP, stream);

        u16* hin = hp0;
        u16* hout = hp1;
        for (int t = 0; t < T_; ++t) {
            lstm_step<2><<<gstep, 256, 0, stream>>>(
                hin, U_, W4rT, xbf + (size_t)t * B_ * F_, F_, W4kT,
                nullptr, bias4, c, hout);
            u16* tmp = hin; hin = hout; hout = tmp;
        }
        gemm2<64, 128, 0, 0, 1, 3><<<dim3(F_ / 128, B_ / 64), 256, 0, stream>>>(
            hin, U_, dT, U_, nullptr, 0, nullptr, 0, nullptr, 0, bd,
            out, (long)OT * F_, pred, U_);
        for (int t = 1; t < OT; ++t) {
            lstm_step<2><<<gstep, 256, 0, stream>>>(
                hin, U_, W4rT, pred, U_, W4kT, nullptr, bias4, c, hout);
            u16* tmp = hin; hin = hout; hout = tmp;
            gemm2<64, 128, 0, 0, 1, 3><<<dim3(F_ / 128, B_ / 64), 256, 0, stream>>>(
                hin, U_, dT, U_, nullptr, 0, nullptr, 0, nullptr, 0, bd,
                out + (size_t)t * F_, (long)OT * F_, pred, U_);
        }
    }
}

// Round 7
// 3234.723 us; speedup vs baseline: 2.8819x; 1.0009x over previous
//
#include <hip/hip_runtime.h>
#include <hip/hip_bf16.h>
#include <cstddef>
#include <cstdint>

typedef __attribute__((ext_vector_type(8))) short short8;
typedef __attribute__((ext_vector_type(4))) float f32x4;
typedef unsigned short u16;
typedef unsigned int u32;

#define B_ 512
#define T_ 48
#define F_ 2048
#define U_ 2048
#define G4 8192
#define OT 24

__device__ __forceinline__ u16 f2bf(float f) {
    __hip_bfloat16 b = __float2bfloat16(f);
    return *reinterpret_cast<u16*>(&b);
}
__device__ __forceinline__ float bf2f(u16 v) {
    union { u32 u; float f; } c;
    c.u = ((u32)v) << 16;
    return c.f;
}

__device__ __forceinline__ void gl_lds16(const void* g, void* l) {
    __builtin_amdgcn_global_load_lds(
        (const __attribute__((address_space(1))) void*)g,
        (__attribute__((address_space(3))) void*)l, 16, 0, 0);
}

// ---------------------------------------------------------------------------
// XCD/L2-aware tile mapping (n-slab per XCD + 4-row epoch walk inside).
// ---------------------------------------------------------------------------
__device__ __forceinline__ void map_tile(int BM, int BN, int& m0, int& n0) {
    const int gx = gridDim.x, gy = gridDim.y;
    int lin = blockIdx.y * gx + blockIdx.x;
    const int nwg = gx * gy;
    const int sn = gx >> 3;
    const int EN = (sn >= 4) ? 4 : sn;
    const int EM = 4;
    bool ok = ((gx & 7) == 0) && ((gy & 3) == 0) && (sn < 4 || (sn & 3) == 0);
    if (ok) {
        int xcd = lin & 7, idx = lin >> 3;
        int epw = EM * EN;
        int e = idx / epw, r = idx % epw;
        int meb = gy / EM;
        int ne = e / meb, me = e % meb;
        int mi = r % EM, nli = r / EM;
        m0 = (me * EM + mi) * BM;
        n0 = (xcd * sn + ne * EN + nli) * BN;
    } else {
        if ((nwg & 7) == 0) {
            int q = nwg >> 3;
            lin = (lin & 7) * q + (lin >> 3);
        }
        m0 = (lin / gx) * BM;
        n0 = (lin % gx) * BN;
    }
}

// ---------------------------------------------------------------------------
// fp32 [R][C] -> bf16 [C][R]; ILV=1 -> gate-interleaved rows n'=(u<<2)|g.
// ---------------------------------------------------------------------------
template <int ILV>
__global__ void transpose_f32_bf16(const float* __restrict__ in,
                                   u16* __restrict__ out, int R, int C) {
    __shared__ float tile[32][33];
    int bx = blockIdx.x * 32;
    int by = blockIdx.y * 32;
    int tx = threadIdx.x, ty = threadIdx.y;
#pragma unroll
    for (int j = 0; j < 32; j += 8)
        tile[ty + j][tx] = in[(size_t)(by + ty + j) * C + bx + tx];
    __syncthreads();
#pragma unroll
    for (int j = 0; j < 32; j += 8) {
        int cidx = bx + ty + j;
        int orow = ILV ? (((cidx & 2047) << 2) | (cidx >> 11)) : cidx;
        out[(size_t)orow * R + by + tx] = f2bf(tile[tx][ty + j]);
    }
}

__global__ void cvt_bf16(const float* __restrict__ in, u16* __restrict__ out, long n) {
    long i = ((long)blockIdx.x * blockDim.x + threadIdx.x) * 4;
    if (i >= n) return;
    f32x4 v = *(const f32x4*)(in + i);
    ushort4 o;
    o.x = f2bf(v[0]); o.y = f2bf(v[1]); o.z = f2bf(v[2]); o.w = f2bf(v[3]);
    *(ushort4*)(out + i) = o;
}

// x [b][t][f] fp32 -> xbf [t][b][f] bf16
__global__ void cvt_x_tmajor(const float* __restrict__ x, u16* __restrict__ xbf) {
    long i = ((long)blockIdx.x * blockDim.x + threadIdx.x) * 4;
    int f = (int)(i & (F_ - 1));
    long bt = i >> 11;
    int t = (int)(bt % T_);
    int b = (int)(bt / T_);
    f32x4 v = *(const f32x4*)(x + i);
    ushort4 o;
    o.x = f2bf(v[0]); o.y = f2bf(v[1]); o.z = f2bf(v[2]); o.w = f2bf(v[3]);
    *(ushort4*)(xbf + ((size_t)t * B_ + b) * F_ + f) = o;
}

__global__ void make_bias4(const float* __restrict__ bias, float* __restrict__ b4) {
    int n = blockIdx.x * 256 + threadIdx.x;
    int g = n & 3, u = n >> 2;
    b4[n] = bias[g * 2048 + u];
}

__global__ void bcomb_k(const u16* __restrict__ W4kT, const float* __restrict__ bd,
                        const float* __restrict__ bias4, float* __restrict__ bc) {
    int lane = threadIdx.x & 63, wid = threadIdx.x >> 6;
    int n = blockIdx.x * 4 + wid;
    const u16* row = W4kT + (size_t)n * U_;
    float s = 0.f;
    for (int j0 = lane * 8; j0 < U_; j0 += 512) {
        short8 v = *(const short8*)&row[j0];
#pragma unroll
        for (int e = 0; e < 8; ++e) s += bd[j0 + e] * bf2f((u16)v[e]);
    }
#pragma unroll
    for (int o = 32; o; o >>= 1) s += __shfl_down(s, o);
    if (lane == 0) bc[n] = bias4[n] + s;
}

// ---------------------------------------------------------------------------
// 3-buffer counted-vmcnt GEMM pipeline (T3/T4). A [M,K] bf16 (lda),
// B^T [N,K] bf16 (ldb=K). BK=64. Loads for 2 future tiles stay in flight
// across raw barriers; vmcnt(12/6/0) + s_barrier guarantees landing for all
// waves before the dependent ds_read. Slot-XOR (r&7) both sides -> 2-way
// (free) bank access. Write-after-read safety: buf (t+2)%3's readers
// finished at iter t-1's trailing barrier.
// ---------------------------------------------------------------------------
template <int BM, int BN, int WR, int WC, int TPB>
__device__ __forceinline__ void gpipe(const u16* __restrict__ A, long lda,
                                      const u16* __restrict__ B, int K,
                                      int m0, int n0, int tid, u16* lds,
                                      f32x4 (&acc)[BM / WR / 16][BN / WC / 16]) {
    constexpr int BK = 64;
    constexpr int MF = BM / WR / 16, NF = BN / WC / 16;
    constexpr int TILE = (BM + BN) * BK;   // elems per buffer
    constexpr int LA = BM * BK / (TPB * 8);
    constexpr int LB = BN * BK / (TPB * 8);
    static_assert(LA + LB == 6, "vmcnt literals assume 6 loads per stage");
    const int lane = tid & 63, wid = tid >> 6;
    const int wr = wid / WC, wc = wid % WC;
    const int r16 = lane & 15, kg = lane >> 4;
    const int NT = K / BK;

    auto stage = [&](int t) {
        if (t >= NT) return;
        const u16* Abase = A + (size_t)m0 * lda + (size_t)t * BK;
        const u16* Bbase = B + (size_t)n0 * (size_t)K + (size_t)t * BK;
        u16* dst = lds + (t % 3) * TILE;
#pragma unroll
        for (int i = 0; i < LA; ++i) {
            int idx = i * TPB + tid;
            int r = idx >> 3, sl = idx & 7;
            gl_lds16(Abase + (size_t)r * lda + ((sl ^ (r & 7)) * 8), dst + idx * 8);
        }
        u16* dstB = dst + BM * BK;
#pragma unroll
        for (int i = 0; i < LB; ++i) {
            int idx = i * TPB + tid;
            int r = idx >> 3, sl = idx & 7;
            gl_lds16(Bbase + (size_t)r * (size_t)K + ((sl ^ (r & 7)) * 8), dstB + idx * 8);
        }
    };
    auto compute = [&](int t) {
        const u16* Ab = lds + (t % 3) * TILE;
        const u16* Bb = Ab + BM * BK;
        __builtin_amdgcn_s_setprio(1);
#pragma unroll
        for (int ks = 0; ks < 2; ++ks) {
            short8 af[MF], bf[NF];
#pragma unroll
            for (int mi = 0; mi < MF; ++mi) {
                int row = wr * (BM / WR) + mi * 16 + r16;
                int s = (ks * 4 + kg) ^ (row & 7);
                af[mi] = *(const short8*)&Ab[row * BK + s * 8];
            }
#pragma unroll
            for (int ni = 0; ni < NF; ++ni) {
                int row = wc * (BN / WC) + ni * 16 + r16;
                int s = (ks * 4 + kg) ^ (row & 7);
                bf[ni] = *(const short8*)&Bb[row * BK + s * 8];
            }
#pragma unroll
            for (int mi = 0; mi < MF; ++mi)
#pragma unroll
                for (int ni = 0; ni < NF; ++ni)
                    acc[mi][ni] = __builtin_amdgcn_mfma_f32_16x16x32_bf16(
                        af[mi], bf[ni], acc[mi][ni], 0, 0, 0);
        }
        __builtin_amdgcn_s_setprio(0);
    };

    stage(0);
    stage(1);
    for (int t = 0; t < NT; ++t) {
        stage(t + 2);
        if (t + 2 < NT)
            asm volatile("s_waitcnt vmcnt(12)\ns_barrier" ::: "memory");
        else if (t + 1 < NT)
            asm volatile("s_waitcnt vmcnt(6)\ns_barrier" ::: "memory");
        else
            asm volatile("s_waitcnt vmcnt(0)\ns_barrier" ::: "memory");
        compute(t);
        asm volatile("s_barrier" ::: "memory");
    }
}

// CM: 0 none, 2 bf16 Cinit. OUTM: 0 fp32, 1 bf16, 2 fp32 (t,b)-remap,
// 3 fp32 + bf16 secondary.
template <int BM, int BN, int WR, int WC, int TPB, int CM, int BIAS, int OUTM>
__global__ __launch_bounds__(TPB) void gemm3(
    const u16* __restrict__ A1, long lda1, const u16* __restrict__ B1, int K1,
    const void* __restrict__ Ci, long ldci, const float* __restrict__ bias,
    void* __restrict__ Co, long ldc, void* __restrict__ Co2, long ldc2) {
    __shared__ __align__(16) u16 lds[3 * (BM + BN) * 64];
    int m0, n0;
    map_tile(BM, BN, m0, n0);
    const int tid = threadIdx.x;

    f32x4 acc[BM / WR / 16][BN / WC / 16] = {};
    gpipe<BM, BN, WR, WC, TPB>(A1, lda1, B1, K1, m0, n0, tid, lds, acc);

    const int lane = tid & 63, wid = tid >> 6;
    const int wr = wid / WC, wc = wid % WC, r16 = lane & 15, rg = lane >> 4;
#pragma unroll
    for (int ni = 0; ni < BN / WC / 16; ++ni) {
        int col = n0 + wc * (BN / WC) + ni * 16 + r16;
        float bv = BIAS ? bias[col] : 0.f;
#pragma unroll
        for (int mi = 0; mi < BM / WR / 16; ++mi) {
#pragma unroll
            for (int r = 0; r < 4; ++r) {
                int row = m0 + wr * (BM / WR) + mi * 16 + rg * 4 + r;
                float v = acc[mi][ni][r] + bv;
                if constexpr (CM == 2) v += bf2f(((const u16*)Ci)[(size_t)row * ldci + col]);
                if constexpr (OUTM == 0) ((float*)Co)[(size_t)row * ldc + col] = v;
                if constexpr (OUTM == 1) ((u16*)Co)[(size_t)row * ldc + col] = f2bf(v);
                if constexpr (OUTM == 2) {
                    int t = row >> 9, b = row & 511;
                    ((float*)Co)[((size_t)b * OT + t) * F_ + col] = v;
                }
                if constexpr (OUTM == 3) {
                    ((float*)Co)[(size_t)row * ldc + col] = v;
                    ((u16*)Co2)[(size_t)row * ldc2 + col] = f2bf(v);
                }
            }
        }
    }
}

// ---------------------------------------------------------------------------
// Fused LSTM step (gate-interleaved weights, n'=(u<<2)|gate).
// z = A1@B1 [+ A2@B2]; + (WARM==1 ? zx : bc4); gates -> c, hout.
// Grid (64,8), 256 thr, BM=64 BN=128, 3-buffer pipeline (72 KB LDS).
// ---------------------------------------------------------------------------
template <int WARM>
__global__ __launch_bounds__(256) void lstm_step(
    const u16* __restrict__ A1, long lda1, const u16* __restrict__ B1,
    const u16* __restrict__ A2, long lda2, const u16* __restrict__ B2,
    const u16* __restrict__ zx, const float* __restrict__ bc4,
    float* __restrict__ c, u16* __restrict__ hout) {
    constexpr int BM = 64, BN = 128;
    __shared__ __align__(16) char smem[3 * (BM + BN) * 64 * 2];  // 72 KB
    u16* lds = (u16*)smem;
    float* zt = (float*)smem;  // 64 x 132 fp32 alias (33.8 KB)

    int m0, n0;
    map_tile(BM, BN, m0, n0);
    const int tid = threadIdx.x;

    f32x4 acc[2][4] = {};
    gpipe<BM, BN, 2, 2, 256>(A1, lda1, B1, U_, m0, n0, tid, lds, acc);
    if constexpr (WARM == 2)
        gpipe<BM, BN, 2, 2, 256>(A2, lda2, B2, U_, m0, n0, tid, lds, acc);

    __syncthreads();
    {
        const int lane = tid & 63, wid = tid >> 6;
        const int wr = wid >> 1, wc = wid & 1, r16 = lane & 15, rg = lane >> 4;
#pragma unroll
        for (int mi = 0; mi < 2; ++mi)
#pragma unroll
            for (int ni = 0; ni < 4; ++ni)
#pragma unroll
                for (int r = 0; r < 4; ++r)
                    zt[(wr * 32 + mi * 16 + rg * 4 + r) * 132 + wc * 64 + ni * 16 + r16] =
                        acc[mi][ni][r];
    }
    __syncthreads();

    const int row = tid >> 5, ul = tid & 31;
    const int ug = (n0 >> 2) + ul;
#pragma unroll
    for (int j = 0; j < 8; ++j) {
        int rr = j * 8 + row;
        f32x4 zv = *(const f32x4*)&zt[rr * 132 + 4 * ul];
        float zi = zv[0], zf = zv[1], zg = zv[2], zo = zv[3];
        if constexpr (WARM == 1) {
            ushort4 zb = *(const ushort4*)&zx[(size_t)(m0 + rr) * G4 + n0 + 4 * ul];
            zi += bf2f(zb.x); zf += bf2f(zb.y); zg += bf2f(zb.z); zo += bf2f(zb.w);
        } else {
            f32x4 bv = *(const f32x4*)&bc4[n0 + 4 * ul];
            zi += bv[0]; zf += bv[1]; zg += bv[2]; zo += bv[3];
        }
        size_t ci = (size_t)(m0 + rr) * U_ + ug;
        float si = 1.f / (1.f + __expf(-zi));
        float sf = 1.f / (1.f + __expf(-zf));
        float so = 1.f / (1.f + __expf(-zo));
        float cc = sf * c[ci] + si * tanhf(zg);
        c[ci] = cc;
        hout[ci] = f2bf(so * tanhf(cc));
    }
}

// ---------------------------------------------------------------------------
extern "C" void kernel_launch(void* const* d_in, const int* in_sizes, int n_in,
                              void* d_out, int out_size, void* d_ws, size_t ws_size,
                              hipStream_t stream) {
    const float* x = (const float*)d_in[0];
    const float* Wk = (const float*)d_in[1];
    const float* Wr = (const float*)d_in[2];
    const float* bias = (const float*)d_in[3];
    const float* Wd = (const float*)d_in[4];
    const float* bd = (const float*)d_in[5];
    float* out = (float*)d_out;

    // d_out doubles as bf16-x storage (t-major): dead until the final pred GEMM.
    u16* xbf = (u16*)d_out;

    auto pad = [](size_t s) { return (s + 255) & ~(size_t)255; };
    const size_t szW4 = (size_t)G4 * U_ * 2;      // 32 MB
    const size_t szDT = (size_t)U_ * F_ * 2;      // 8 MB
    const size_t szB4 = (size_t)G4 * 4;           // 32 KB
    const size_t szH = (size_t)OT * B_ * U_ * 2;  // 48 MB
    const size_t szHP = (size_t)B_ * U_ * 2;      // 2 MB
    const size_t szC = (size_t)B_ * U_ * 4;       // 4 MB
    const size_t szZX1 = (size_t)B_ * G4 * 2;     // 8.39 MB / step (bf16)
    const size_t SLOT = (size_t)B_ * U_;

    const size_t needMain = pad(szW4) * 3 + pad(szDT) * 2 + pad(szB4) * 2 +
                            pad(szH) + pad(szHP) * 2 + pad(szC) + pad(szZX1);
    const int path = ws_size >= needMain ? 1 : 0;

    char* p = (char*)d_ws;
    auto alloc = [&](size_t bytes) { void* r = p; p += (bytes + 255) & ~(size_t)255; return r; };

    dim3 tb32(32, 8);
    const dim3 gstep(64, 8);

    if (path == 1) {
        u16* W4kT = (u16*)alloc(szW4);
        u16* W4rT = (u16*)alloc(szW4);
        u16* W4cT = (u16*)alloc(szW4);
        u16* dT = (u16*)alloc(szDT);
        u16* dbf = (u16*)alloc(szDT);
        float* bias4 = (float*)alloc(szB4);
        float* bc4 = (float*)alloc(szB4);
        u16* H = (u16*)alloc(szH);
        u16* hp0 = (u16*)alloc(szHP);
        u16* hp1 = (u16*)alloc(szHP);
        float* c = (float*)alloc(szC);

        size_t avail = ws_size - (size_t)(p - (char*)d_ws);
        int chunk = (int)(avail / szZX1);
        if (chunk > T_) chunk = T_;
        u16* ZX = (u16*)alloc((size_t)chunk * szZX1);

        cvt_x_tmajor<<<(B_ * T_ * F_ / 4 + 255) / 256, 256, 0, stream>>>(x, xbf);
        transpose_f32_bf16<1><<<dim3(G4 / 32, F_ / 32), tb32, 0, stream>>>(Wk, W4kT, F_, G4);
        transpose_f32_bf16<1><<<dim3(G4 / 32, U_ / 32), tb32, 0, stream>>>(Wr, W4rT, U_, G4);
        transpose_f32_bf16<0><<<dim3(F_ / 32, U_ / 32), tb32, 0, stream>>>(Wd, dT, U_, F_);
        cvt_bf16<<<(U_ * F_ / 4 + 255) / 256, 256, 0, stream>>>(Wd, dbf, (long)U_ * F_);
        make_bias4<<<G4 / 256, 256, 0, stream>>>(bias, bias4);
        bcomb_k<<<G4 / 4, 256, 0, stream>>>(W4kT, bd, bias4, bc4);

        // W4cT[n'][k] = W4rT[n'][k] + sum_j W4kT[n'][j] * Wd[k][j]
        gemm3<256, 128, 4, 2, 512, 2, 0, 1><<<dim3(U_ / 128, G4 / 256), 512, 0, stream>>>(
            W4kT, U_, dbf, F_, W4rT, U_, nullptr, W4cT, U_, nullptr, 0);

        hipMemsetAsync(c, 0, szC, stream);
        hipMemsetAsync(hp0, 0, szHP, stream);

        for (int t0 = 0; t0 < T_; t0 += chunk) {
            int nc = chunk < T_ - t0 ? chunk : T_ - t0;
            // ZX[tt] = x_tt @ W4kT + bias4  (bf16, interleaved cols)
            if ((nc * B_) % 256 == 0) {
                gemm3<256, 128, 4, 2, 512, 0, 1, 1>
                    <<<dim3(G4 / 128, nc * B_ / 256), 512, 0, stream>>>(
                        xbf + (size_t)t0 * B_ * F_, F_, W4kT, F_, nullptr, 0,
                        bias4, ZX, G4, nullptr, 0);
            } else {
                gemm3<64, 128, 2, 2, 256, 0, 1, 1>
                    <<<dim3(G4 / 128, nc * B_ / 64), 256, 0, stream>>>(
                        xbf + (size_t)t0 * B_ * F_, F_, W4kT, F_, nullptr, 0,
                        bias4, ZX, G4, nullptr, 0);
            }
            for (int t = t0; t < t0 + nc; ++t) {
                const u16* hin = (t & 1) ? hp1 : hp0;
                u16* hout = (t == T_ - 1) ? H : ((t & 1) ? hp0 : hp1);
                lstm_step<1><<<gstep, 256, 0, stream>>>(
                    hin, U_, W4rT, nullptr, 0, nullptr,
                    ZX + (size_t)(t - t0) * B_ * G4, nullptr, c, hout);
            }
        }
        for (int t = 1; t < OT; ++t) {
            lstm_step<0><<<gstep, 256, 0, stream>>>(
                H + (size_t)(t - 1) * SLOT, U_, W4cT, nullptr, 0, nullptr,
                nullptr, bc4, c, H + (size_t)t * SLOT);
        }
        // out[b][t][f] = H[t][b] @ Wd + bd
        gemm3<256, 128, 4, 2, 512, 0, 1, 2><<<dim3(F_ / 128, OT * B_ / 256), 512, 0, stream>>>(
            H, U_, dT, U_, nullptr, 0, bd, out, F_, nullptr, 0);
    } else {
        // Fallback (~82 MB): no ZX hoist, no Wcomb, per-step pred GEMM.
        u16* W4kT = (u16*)alloc(szW4);
        u16* W4rT = (u16*)alloc(szW4);
        u16* dT = (u16*)alloc(szDT);
        float* bias4 = (float*)alloc(szB4);
        u16* hp0 = (u16*)alloc(szHP);
        u16* hp1 = (u16*)alloc(szHP);
        u16* pred = (u16*)alloc(szHP);
        float* c = (float*)alloc(szC);

        cvt_x_tmajor<<<(B_ * T_ * F_ / 4 + 255) / 256, 256, 0, stream>>>(x, xbf);
        transpose_f32_bf16<1><<<dim3(G4 / 32, F_ / 32), tb32, 0, stream>>>(Wk, W4kT, F_, G4);
        transpose_f32_bf16<1><<<dim3(G4 / 32, U_ / 32), tb32, 0, stream>>>(Wr, W4rT, U_, G4);
        transpose_f32_bf16<0><<<dim3(F_ / 32, U_ / 32), tb32, 0, stream>>>(Wd, dT, U_, F_);
        make_bias4<<<G4 / 256, 256, 0, stream>>>(bias, bias4);
        hipMemsetAsync(c, 0, szC, stream);
        hipMemsetAsync(hp0, 0, szHP, stream);

        u16* hin = hp0;
        u16* hout = hp1;
        for (int t = 0; t < T_; ++t) {
            lstm_step<2><<<gstep, 256, 0, stream>>>(
                hin, U_, W4rT, xbf + (size_t)t * B_ * F_, F_, W4kT,
                nullptr, bias4, c, hout);
            u16* tmp = hin; hin = hout; hout = tmp;
        }
        gemm3<64, 128, 2, 2, 256, 0, 1, 3><<<dim3(F_ / 128, B_ / 64), 256, 0, stream>>>(
            hin, U_, dT, U_, nullptr, 0, bd, out, (long)OT * F_, pred, U_);
        for (int t = 1; t < OT; ++t) {
            lstm_step<2><<<gstep, 256, 0, stream>>>(
                hin, U_, W4rT, pred, U_, W4kT, nullptr, bias4, c, hout);
            u16* tmp = hin; hin = hout; hout = tmp;
            gemm3<64, 128, 2, 2, 256, 0, 1, 3><<<dim3(F_ / 128, B_ / 64), 256, 0, stream>>>(
                hin, U_, dT, U_, nullptr, 0, bd, out + (size_t)t * F_, (long)OT * F_, pred, U_);
        }
    }
}